// Round 4
// baseline (215.715 us; speedup 1.0000x reference)
//
#include <hip/hip_runtime.h>
#include <hip/hip_bf16.h>

// GAT layer: h = doc@W + Wb; s1 = h@a1, s2 = h@a2;
// score[i,j] = lrelu(s1[i]+s2[j]+ab); att = softmax_rows(score); out = lrelu(att@h)
// N=8192, IN=512, D=256. Outputs: out (8192*256) then att (8192*8192), fp32.
//
// exp(lrelu(s1a+s2j)) = (s2j >= -s1a) ? exp(s1a)*e2[j] : exp(.1*s1a)*e02[j]
// with e2[j]=exp(s2[j]), e02[j]=exp(.1*s2[j]) -> no transcendentals in N^2 loops.

typedef __attribute__((ext_vector_type(4))) float f32x4;
typedef __attribute__((ext_vector_type(2))) float f32x2;
typedef __attribute__((ext_vector_type(8))) short short8;
typedef __attribute__((ext_vector_type(4))) unsigned short ushort4v;

#define SLOPE 0.1f
#define NROW 8192
#define DDIM 256

__device__ __forceinline__ float lrelu(float x){ return fmaxf(x, SLOPE * x); }

// round-to-nearest-even fp32 -> bf16
__device__ __forceinline__ unsigned short f2bf(float f){
  union { float f; unsigned u; } v; v.f = f;
  unsigned r = (v.u + 0x7fffu + ((v.u >> 16) & 1u)) >> 16;
  return (unsigned short)r;
}

// two fp32 -> packed 2x bf16 (RNE), single HW instr
__device__ __forceinline__ unsigned cvt_pk_bf16(float lo, float hi){
  unsigned r;
  asm("v_cvt_pk_bf16_f32 %0, %1, %2" : "=v"(r) : "v"(lo), "v"(hi));
  return r;
}

// ---------------- K1: h = doc @ W + Wb (fp32) + ht = h^T bf16 ----------------
__global__ __launch_bounds__(256) void k_h(
    const float* __restrict__ doc, const float* __restrict__ W,
    const float* __restrict__ Wb, float* __restrict__ h,
    unsigned short* __restrict__ ht)
{
  __shared__ __align__(16) float At[16][68];
  __shared__ __align__(16) float Bs[16][68];
  const int t  = threadIdx.x;
  const int cb = blockIdx.x * 64;
  const int rb = blockIdx.y * 64;
  const int tx = t & 15, ty = t >> 4;

  float acc[4][4] = {};
  const int srow = t >> 2, skq = t & 3;
  const int bk = t >> 4, bc = t & 15;

  for (int kk = 0; kk < 512; kk += 16) {
    f32x4 av = *reinterpret_cast<const f32x4*>(doc + (size_t)(rb + srow) * 512 + kk + skq * 4);
    f32x4 wv = *reinterpret_cast<const f32x4*>(W + (size_t)(kk + bk) * 256 + cb + bc * 4);
    __syncthreads();
    At[skq * 4 + 0][srow] = av[0];
    At[skq * 4 + 1][srow] = av[1];
    At[skq * 4 + 2][srow] = av[2];
    At[skq * 4 + 3][srow] = av[3];
    *reinterpret_cast<f32x4*>(&Bs[bk][bc * 4]) = wv;
    __syncthreads();
#pragma unroll
    for (int k = 0; k < 16; ++k) {
      f32x4 a4 = *reinterpret_cast<const f32x4*>(&At[k][ty * 4]);
      f32x4 b4 = *reinterpret_cast<const f32x4*>(&Bs[k][tx * 4]);
#pragma unroll
      for (int i = 0; i < 4; ++i)
#pragma unroll
        for (int j = 0; j < 4; ++j)
          acc[i][j] = fmaf(a4[i], b4[j], acc[i][j]);
    }
  }

  float bias[4];
#pragma unroll
  for (int j = 0; j < 4; ++j) bias[j] = Wb[cb + tx * 4 + j];

#pragma unroll
  for (int i = 0; i < 4; ++i) {
    const int r = rb + ty * 4 + i;
    f32x4 o;
#pragma unroll
    for (int j = 0; j < 4; ++j) o[j] = acc[i][j] + bias[j];
    *reinterpret_cast<f32x4*>(h + (size_t)r * 256 + cb + tx * 4) = o;
  }
#pragma unroll
  for (int j = 0; j < 4; ++j) {
    const int c = cb + tx * 4 + j;
    ushort4v u;
#pragma unroll
    for (int i = 0; i < 4; ++i) u[i] = f2bf(acc[i][j] + bias[j]);
    *reinterpret_cast<ushort4v*>(ht + (size_t)c * 8192 + rb + ty * 4) = u;
  }
}

// ---------------- K2: s1,s2 + exp tables e2=exp(s2), e02=exp(.1*s2) ----------------
__global__ __launch_bounds__(256) void k_s12(
    const float* __restrict__ h, const float* __restrict__ a,
    float* __restrict__ s1, float* __restrict__ s2,
    float* __restrict__ e2, float* __restrict__ e02)
{
  const int t = threadIdx.x, w = t >> 6, l = t & 63;
  float a1[4], a2[4];
#pragma unroll
  for (int q = 0; q < 4; ++q) { a1[q] = a[l + q * 64]; a2[q] = a[256 + l + q * 64]; }
  const int rbase = blockIdx.x * 32 + w * 8;
  for (int rr = 0; rr < 8; ++rr) {
    const int r = rbase + rr;
    float v1 = 0.f, v2 = 0.f;
#pragma unroll
    for (int q = 0; q < 4; ++q) {
      float hv = h[(size_t)r * 256 + l + q * 64];
      v1 = fmaf(hv, a1[q], v1);
      v2 = fmaf(hv, a2[q], v2);
    }
#pragma unroll
    for (int off = 32; off > 0; off >>= 1) { v1 += __shfl_down(v1, off); v2 += __shfl_down(v2, off); }
    if (l == 0) {
      s1[r] = v1; s2[r] = v2;
      e2[r] = __expf(v2); e02[r] = __expf(SLOPE * v2);
    }
  }
}

// ---------------- K3: per-row Z -> rowinfo {E1*iz, E01*iz, T, iz} ----------------
__global__ __launch_bounds__(256) void k_z(
    const float* __restrict__ s1, const float* __restrict__ e2g,
    const float* __restrict__ e02g, const float* __restrict__ abp,
    float* __restrict__ rowinfo)
{
  __shared__ __align__(16) f32x2 ep[8192];  // 64 KB
  const int t = threadIdx.x;
  for (int i = t; i < 8192; i += 256) ep[i] = (f32x2){e2g[i], e02g[i]};
  __syncthreads();
  const int w = t >> 6, l = t & 63;
  const float ab = abp[0];
  const int rb = blockIdx.x * 16 + w * 4;
  for (int rr = 0; rr < 4; ++rr) {
    const int r = rb + rr;
    const float s1a = s1[r] + ab;
    const float E1 = __expf(s1a), E01 = __expf(SLOPE * s1a), T = __expf(-s1a);
    float zA = 0.f, zB = 0.f;
#pragma unroll 4
    for (int i = l; i < 8192; i += 64) {
      f32x2 e = ep[i];
      const bool c = (e.x >= T);
      zA += c ? e.x : 0.f;
      zB += c ? 0.f : e.y;
    }
#pragma unroll
    for (int off = 32; off > 0; off >>= 1) { zA += __shfl_down(zA, off); zB += __shfl_down(zB, off); }
    if (l == 0) {
      const float z = E1 * zA + E01 * zB;
      const float iz = 1.0f / z;
      f32x4 ri = (f32x4){E1 * iz, E01 * iz, T, iz};
      *reinterpret_cast<f32x4*>(rowinfo + (size_t)r * 4) = ri;
    }
  }
}

// ---------------- K4: att + partial out via MFMA, split-K ----------------
// grid (KS, 256). Block: 32 rows x 256 cols, 4 waves, 64-k step.
// Wave w = generation task (rt = w&1 row-tile, kh = w>>1 k-half):
//   writer lane (r16 = l>>2, jc = l&3) computes p for row rt*16+r16,
//   k-local {jc*4..+3, 16+jc*4..+3} -> att stores are 64 B contiguous runs
//   (4 lanes x 16 B); bf16 halves scattered into A-frag LDS positions via
//   2x ds_write_b64. Consumers read 4 frag sets, 16 MFMA per 64-k.
// Barrier = s_barrier + lgkmcnt(0) only (att nt-stores stay in flight).
__global__ __launch_bounds__(256, 4) void k_att(
    const float* __restrict__ rowinfo, const float* __restrict__ e2g,
    const float* __restrict__ e02g, const unsigned short* __restrict__ ht,
    float* __restrict__ att, float* __restrict__ part, int CHUNK)
{
  __shared__ __align__(16) short8 pls[2][4][64];   // 8 KB: [par][set][lane]
  char* plsb = reinterpret_cast<char*>(&pls[0][0][0]);

  const int t = threadIdx.x, w = t >> 6, l = t & 63;
  const int lr = l & 15, lg = l >> 4;
  const int rb = blockIdx.y * 32;
  const int kbase = blockIdx.x * CHUNK;

  // ---- writer role ----
  const int r16 = l >> 2, jc = l & 3;
  const int wrt = w & 1, wkh = w >> 1;
  const int prow = rb + wrt * 16 + r16;
  const f32x4 ri = *reinterpret_cast<const f32x4*>(rowinfo + (size_t)prow * 4);
  const float E1z = ri[0], E01z = ri[1], T = ri[2];
  float* attrow = att + (size_t)prow * 8192 + kbase + wkh * 32;
  const float* e2p  = e2g  + kbase + wkh * 32;
  const float* e02p = e02g + kbase + wkh * 32;
  // frag LDS byte offsets (within one par buffer): set = w
  const int fragoff1 = w * 1024 + ((jc >> 1) * 16 + r16) * 16 + (jc & 1) * 8;
  const int fragoff2 = fragoff1 + 512;   // k-chunk +16 -> fl += 32

  f32x4 acc[2][4];
#pragma unroll
  for (int rt = 0; rt < 2; ++rt)
#pragma unroll
    for (int ct = 0; ct < 4; ++ct) acc[rt][ct] = (f32x4){0.f, 0.f, 0.f, 0.f};

  const unsigned short* hbase = ht + (size_t)(w * 64 + lr) * 8192 + kbase + lg * 8;

  for (int kk = 0; kk < CHUNK; kk += 64) {
    const int par = (kk >> 6) & 1;
    const int jlo = kk + jc * 4;

    // e-table loads FIRST (p-gen waits these; ht loads stay in flight after)
    const f32x4 eA = *reinterpret_cast<const f32x4*>(e2p + jlo);
    const f32x4 eB = *reinterpret_cast<const f32x4*>(e2p + jlo + 16);
    const f32x4 fA = *reinterpret_cast<const f32x4*>(e02p + jlo);
    const f32x4 fB = *reinterpret_cast<const f32x4*>(e02p + jlo + 16);

    // B fragments for this 64-k step (L1/L2 resident)
    short8 bf[2][4];
#pragma unroll
    for (int kh = 0; kh < 2; ++kh)
#pragma unroll
      for (int ct = 0; ct < 4; ++ct)
        bf[kh][ct] = *reinterpret_cast<const short8*>(
            hbase + kk + kh * 32 + (size_t)ct * 16 * 8192);

    f32x4 pA, pB;
#pragma unroll
    for (int q = 0; q < 4; ++q) {
      const bool ca = (eA[q] >= T);
      pA[q] = (ca ? E1z : E01z) * (ca ? eA[q] : fA[q]);
      const bool cb2 = (eB[q] >= T);
      pB[q] = (cb2 ? E1z : E01z) * (cb2 ? eB[q] : fB[q]);
    }
    // att: 4 consecutive lanes -> 64 B contiguous runs (full sectors)
    __builtin_nontemporal_store(pA, reinterpret_cast<f32x4*>(attrow + jlo));
    __builtin_nontemporal_store(pB, reinterpret_cast<f32x4*>(attrow + jlo + 16));

    // bf16 halves -> A-frag positions (scattered ds_write_b64)
    uint2 loU, hiU;
    loU.x = cvt_pk_bf16(pA[0], pA[1]); loU.y = cvt_pk_bf16(pA[2], pA[3]);
    hiU.x = cvt_pk_bf16(pB[0], pB[1]); hiU.y = cvt_pk_bf16(pB[2], pB[3]);
    *reinterpret_cast<uint2*>(plsb + par * 4096 + fragoff1) = loU;
    *reinterpret_cast<uint2*>(plsb + par * 4096 + fragoff2) = hiU;

    // LDS handoff barrier WITHOUT vmcnt drain
    asm volatile("s_waitcnt lgkmcnt(0)\n\ts_barrier" ::: "memory");

    const short8* pbuf = reinterpret_cast<const short8*>(plsb + par * 4096);
    const short8 a00 = pbuf[0 * 64 + l];   // (rt0, kh0)
    const short8 a10 = pbuf[1 * 64 + l];   // (rt1, kh0)
    const short8 a01 = pbuf[2 * 64 + l];   // (rt0, kh1)
    const short8 a11 = pbuf[3 * 64 + l];   // (rt1, kh1)

    __builtin_amdgcn_s_setprio(1);
#pragma unroll
    for (int ct = 0; ct < 4; ++ct) {
      acc[0][ct] = __builtin_amdgcn_mfma_f32_16x16x32_bf16(a00, bf[0][ct], acc[0][ct], 0, 0, 0);
      acc[1][ct] = __builtin_amdgcn_mfma_f32_16x16x32_bf16(a10, bf[0][ct], acc[1][ct], 0, 0, 0);
    }
#pragma unroll
    for (int ct = 0; ct < 4; ++ct) {
      acc[0][ct] = __builtin_amdgcn_mfma_f32_16x16x32_bf16(a01, bf[1][ct], acc[0][ct], 0, 0, 0);
      acc[1][ct] = __builtin_amdgcn_mfma_f32_16x16x32_bf16(a11, bf[1][ct], acc[1][ct], 0, 0, 0);
    }
    __builtin_amdgcn_s_setprio(0);
  }

  // epilogue: raw partial sums (lrelu deferred to reduce)
  float* pb = part + (size_t)blockIdx.x * ((size_t)NROW * DDIM);
#pragma unroll
  for (int rt = 0; rt < 2; ++rt)
#pragma unroll
    for (int ct = 0; ct < 4; ++ct)
#pragma unroll
      for (int q = 0; q < 4; ++q)
        pb[(size_t)(rb + rt * 16 + lg * 4 + q) * 256 + w * 64 + ct * 16 + lr] = acc[rt][ct][q];
}

// ---------------- K5: out = lrelu(sum_k part[k]) ----------------
__global__ __launch_bounds__(256) void k_reduce(
    const float* __restrict__ part, float* __restrict__ out, int KS)
{
  const size_t idx = ((size_t)blockIdx.x * 256 + threadIdx.x) * 4;
  f32x4 s = *reinterpret_cast<const f32x4*>(part + idx);
  for (int k = 1; k < KS; ++k) {
    const f32x4 v = *reinterpret_cast<const f32x4*>(part + (size_t)k * NROW * DDIM + idx);
#pragma unroll
    for (int q = 0; q < 4; ++q) s[q] += v[q];
  }
#pragma unroll
  for (int q = 0; q < 4; ++q) s[q] = lrelu(s[q]);
  *reinterpret_cast<f32x4*>(out + idx) = s;
}

extern "C" void kernel_launch(void* const* d_in, const int* in_sizes, int n_in,
                              void* d_out, int out_size, void* d_ws, size_t ws_size,
                              hipStream_t stream)
{
  const float* doc = (const float*)d_in[0];
  const float* W   = (const float*)d_in[1];
  const float* Wb  = (const float*)d_in[2];
  const float* a   = (const float*)d_in[3];
  const float* ab  = (const float*)d_in[4];

  float* out = (float*)d_out;                 // 8192*256
  float* att = out + (size_t)8192 * 256;      // 8192*8192

  char* ws = (char*)d_ws;
  float* h           = (float*)ws;                                      // 8 MB
  unsigned short* ht = (unsigned short*)(ws + (size_t)8 * 1024 * 1024); // 4 MB
  char* tb           = ws + (size_t)12 * 1024 * 1024;
  float* s1  = (float*)tb;
  float* s2  = s1 + 8192;
  float* e2  = s2 + 8192;
  float* e02 = e2 + 8192;
  float* rowinfo = e02 + 8192;
  const size_t base = (size_t)12 * 1024 * 1024 + 288 * 1024;
  const size_t partBytes = (size_t)NROW * DDIM * sizeof(float);  // 8 MB per slice

  int KS = 1;
  for (int c = 4; c >= 1; c >>= 1)
    if (base + (size_t)c * partBytes <= ws_size) { KS = c; break; }
  float* part = (float*)(ws + base);
  const int CHUNK = NROW / KS;

  hipLaunchKernelGGL(k_h,      dim3(4, 128),   dim3(256), 0, stream, doc, W, Wb, h, ht);
  hipLaunchKernelGGL(k_s12,    dim3(256),      dim3(256), 0, stream, h, a, s1, s2, e2, e02);
  hipLaunchKernelGGL(k_z,      dim3(512),      dim3(256), 0, stream, s1, e2, e02, ab, rowinfo);
  hipLaunchKernelGGL(k_att,    dim3(KS, 256),  dim3(256), 0, stream, rowinfo, e2, e02, ht, att, part, CHUNK);
  hipLaunchKernelGGL(k_reduce, dim3(2048),     dim3(256), 0, stream, part, out, KS);
}

// Round 5
// 211.619 us; speedup vs baseline: 1.0194x; 1.0194x over previous
//
#include <hip/hip_runtime.h>
#include <hip/hip_bf16.h>

// GAT layer: h = doc@W + Wb; s1 = h@a1, s2 = h@a2;
// score[i,j] = lrelu(s1[i]+s2[j]+ab); att = softmax_rows(score); out = lrelu(att@h)
// N=8192, IN=512, D=256. Outputs: out (8192*256) then att (8192*8192), fp32.
//
// exp(lrelu(s1a+s2j)) = (s2j >= -s1a) ? exp(s1a)*e2[j] : exp(.1*s1a)*e02[j]
// with e2[j]=exp(s2[j]), e02[j]=exp(.1*s2[j]) -> no transcendentals in N^2 loops.

typedef __attribute__((ext_vector_type(4))) float f32x4;
typedef __attribute__((ext_vector_type(2))) float f32x2;
typedef __attribute__((ext_vector_type(8))) short short8;
typedef __attribute__((ext_vector_type(4))) unsigned short ushort4v;

#define SLOPE 0.1f
#define NROW 8192
#define DDIM 256

__device__ __forceinline__ float lrelu(float x){ return fmaxf(x, SLOPE * x); }

// round-to-nearest-even fp32 -> bf16
__device__ __forceinline__ unsigned short f2bf(float f){
  union { float f; unsigned u; } v; v.f = f;
  unsigned r = (v.u + 0x7fffu + ((v.u >> 16) & 1u)) >> 16;
  return (unsigned short)r;
}

// two fp32 -> packed 2x bf16 (RNE), single HW instr
__device__ __forceinline__ unsigned cvt_pk_bf16(float lo, float hi){
  unsigned r;
  asm("v_cvt_pk_bf16_f32 %0, %1, %2" : "=v"(r) : "v"(lo), "v"(hi));
  return r;
}

// ---------------- K1: h = doc @ W + Wb (fp32) + ht = h^T bf16 ----------------
__global__ __launch_bounds__(256) void k_h(
    const float* __restrict__ doc, const float* __restrict__ W,
    const float* __restrict__ Wb, float* __restrict__ h,
    unsigned short* __restrict__ ht)
{
  __shared__ __align__(16) float At[16][68];
  __shared__ __align__(16) float Bs[16][68];
  const int t  = threadIdx.x;
  const int cb = blockIdx.x * 64;
  const int rb = blockIdx.y * 64;
  const int tx = t & 15, ty = t >> 4;

  float acc[4][4] = {};
  const int srow = t >> 2, skq = t & 3;
  const int bk = t >> 4, bc = t & 15;

  for (int kk = 0; kk < 512; kk += 16) {
    f32x4 av = *reinterpret_cast<const f32x4*>(doc + (size_t)(rb + srow) * 512 + kk + skq * 4);
    f32x4 wv = *reinterpret_cast<const f32x4*>(W + (size_t)(kk + bk) * 256 + cb + bc * 4);
    __syncthreads();
    At[skq * 4 + 0][srow] = av[0];
    At[skq * 4 + 1][srow] = av[1];
    At[skq * 4 + 2][srow] = av[2];
    At[skq * 4 + 3][srow] = av[3];
    *reinterpret_cast<f32x4*>(&Bs[bk][bc * 4]) = wv;
    __syncthreads();
#pragma unroll
    for (int k = 0; k < 16; ++k) {
      f32x4 a4 = *reinterpret_cast<const f32x4*>(&At[k][ty * 4]);
      f32x4 b4 = *reinterpret_cast<const f32x4*>(&Bs[k][tx * 4]);
#pragma unroll
      for (int i = 0; i < 4; ++i)
#pragma unroll
        for (int j = 0; j < 4; ++j)
          acc[i][j] = fmaf(a4[i], b4[j], acc[i][j]);
    }
  }

  float bias[4];
#pragma unroll
  for (int j = 0; j < 4; ++j) bias[j] = Wb[cb + tx * 4 + j];

#pragma unroll
  for (int i = 0; i < 4; ++i) {
    const int r = rb + ty * 4 + i;
    f32x4 o;
#pragma unroll
    for (int j = 0; j < 4; ++j) o[j] = acc[i][j] + bias[j];
    *reinterpret_cast<f32x4*>(h + (size_t)r * 256 + cb + tx * 4) = o;
  }
#pragma unroll
  for (int j = 0; j < 4; ++j) {
    const int c = cb + tx * 4 + j;
    ushort4v u;
#pragma unroll
    for (int i = 0; i < 4; ++i) u[i] = f2bf(acc[i][j] + bias[j]);
    *reinterpret_cast<ushort4v*>(ht + (size_t)c * 8192 + rb + ty * 4) = u;
  }
}

// ---------------- K2: s1,s2 + exp tables e2=exp(s2), e02=exp(.1*s2) ----------------
__global__ __launch_bounds__(256) void k_s12(
    const float* __restrict__ h, const float* __restrict__ a,
    float* __restrict__ s1, float* __restrict__ s2,
    float* __restrict__ e2, float* __restrict__ e02)
{
  const int t = threadIdx.x, w = t >> 6, l = t & 63;
  float a1[4], a2[4];
#pragma unroll
  for (int q = 0; q < 4; ++q) { a1[q] = a[l + q * 64]; a2[q] = a[256 + l + q * 64]; }
  const int rbase = blockIdx.x * 32 + w * 8;
  for (int rr = 0; rr < 8; ++rr) {
    const int r = rbase + rr;
    float v1 = 0.f, v2 = 0.f;
#pragma unroll
    for (int q = 0; q < 4; ++q) {
      float hv = h[(size_t)r * 256 + l + q * 64];
      v1 = fmaf(hv, a1[q], v1);
      v2 = fmaf(hv, a2[q], v2);
    }
#pragma unroll
    for (int off = 32; off > 0; off >>= 1) { v1 += __shfl_down(v1, off); v2 += __shfl_down(v2, off); }
    if (l == 0) {
      s1[r] = v1; s2[r] = v2;
      e2[r] = __expf(v2); e02[r] = __expf(SLOPE * v2);
    }
  }
}

// ---------------- K3: per-row Z -> rowinfo {E1*iz, E01*iz, T, iz} ----------------
__global__ __launch_bounds__(256) void k_z(
    const float* __restrict__ s1, const float* __restrict__ e2g,
    const float* __restrict__ e02g, const float* __restrict__ abp,
    float* __restrict__ rowinfo)
{
  __shared__ __align__(16) f32x2 ep[8192];  // 64 KB
  const int t = threadIdx.x;
  for (int i = t; i < 8192; i += 256) ep[i] = (f32x2){e2g[i], e02g[i]};
  __syncthreads();
  const int w = t >> 6, l = t & 63;
  const float ab = abp[0];
  const int rb = blockIdx.x * 16 + w * 4;
  for (int rr = 0; rr < 4; ++rr) {
    const int r = rb + rr;
    const float s1a = s1[r] + ab;
    const float E1 = __expf(s1a), E01 = __expf(SLOPE * s1a), T = __expf(-s1a);
    float zA = 0.f, zB = 0.f;
#pragma unroll 4
    for (int i = l; i < 8192; i += 64) {
      f32x2 e = ep[i];
      const bool c = (e.x >= T);
      zA += c ? e.x : 0.f;
      zB += c ? 0.f : e.y;
    }
#pragma unroll
    for (int off = 32; off > 0; off >>= 1) { zA += __shfl_down(zA, off); zB += __shfl_down(zB, off); }
    if (l == 0) {
      const float z = E1 * zA + E01 * zB;
      const float iz = 1.0f / z;
      f32x4 ri = (f32x4){E1 * iz, E01 * iz, T, iz};
      *reinterpret_cast<f32x4*>(rowinfo + (size_t)r * 4) = ri;
    }
  }
}

// ---------------- K4: att + partial out via MFMA, split-K ----------------
// grid (128, KS): x = row-block (64 rows), y = k-slice (CHUNK k each).
// 4 waves/block, 32-k step. Wave w generates p for rows rb+w*16..+15 and
// consumes cols w*64..+63 for all 4 row-tiles.
// Writer lanes: r8 = l>>3, jc = l&7; two passes (rows r8 / r8+8), each pass
// covers j = jc*4..+3 -> one nt-store instr = 8 rows x 128 B CONTIGUOUS
// (full lines; fixes nontemporal partial-sector write amplification).
// bf16 A-frag halves scattered to MFMA layout via 2x ds_write_b64.
// Barrier = s_barrier + lgkmcnt(0) only (att nt-stores stay in flight).
__global__ __launch_bounds__(256, 4) void k_att(
    const float* __restrict__ rowinfo, const float* __restrict__ e2g,
    const float* __restrict__ e02g, const unsigned short* __restrict__ ht,
    float* __restrict__ att, float* __restrict__ part, int CHUNK)
{
  extern __shared__ __align__(16) char smem[];
  char* plsb  = smem;                                    // [2][4][64] short8 = 8 KB
  float* e2s  = reinterpret_cast<float*>(smem + 8192);   // CHUNK
  float* e02s = e2s + CHUNK;                             // CHUNK

  const int t = threadIdx.x, w = t >> 6, l = t & 63;
  const int lr = l & 15, lg = l >> 4;
  const int rb = blockIdx.x * 64;
  const int kbase = blockIdx.y * CHUNK;

  for (int i = t * 4; i < CHUNK; i += 1024) {
    *reinterpret_cast<f32x4*>(e2s + i)  = *reinterpret_cast<const f32x4*>(e2g + kbase + i);
    *reinterpret_cast<f32x4*>(e02s + i) = *reinterpret_cast<const f32x4*>(e02g + kbase + i);
  }

  // ---- writer role ----
  const int r8 = l >> 3, jc = l & 7;
  const int rowA = rb + w * 16 + r8;       // pass A row
  const int rowB = rowA + 8;               // pass B row
  const f32x4 riA = *reinterpret_cast<const f32x4*>(rowinfo + (size_t)rowA * 4);
  const f32x4 riB = *reinterpret_cast<const f32x4*>(rowinfo + (size_t)rowB * 4);
  const float E1zA = riA[0], E01zA = riA[1], TA = riA[2];
  const float E1zB = riB[0], E01zB = riB[1], TB = riB[2];
  float* attA = att + (size_t)rowA * 8192 + kbase + jc * 4;
  float* attB = att + (size_t)rowB * 8192 + kbase + jc * 4;
  // A-frag LDS byte offsets: set w, frag-lane (jc>>1)*16 + row16, byte (jc&1)*8
  const int fragA = w * 1024 + ((jc >> 1) * 16 + r8) * 16 + (jc & 1) * 8;
  const int fragB = fragA + 128;   // row16 += 8

  __syncthreads();

  f32x4 acc[4][4];
#pragma unroll
  for (int rt = 0; rt < 4; ++rt)
#pragma unroll
    for (int ct = 0; ct < 4; ++ct) acc[rt][ct] = (f32x4){0.f, 0.f, 0.f, 0.f};

  const unsigned short* hbase = ht + (size_t)(w * 64 + lr) * 8192 + kbase + lg * 8;

  for (int kk = 0; kk < CHUNK; kk += 32) {
    const int par = (kk >> 5) & 1;

    // e-table reads (LDS; same j-window for both passes)
    const f32x4 eA = *reinterpret_cast<const f32x4*>(e2s + kk + jc * 4);
    const f32x4 fA = *reinterpret_cast<const f32x4*>(e02s + kk + jc * 4);

    // B fragments (L1/L2-resident ht), issued before p-gen
    const short8 b0 = *reinterpret_cast<const short8*>(hbase + kk);
    const short8 b1 = *reinterpret_cast<const short8*>(hbase + kk + (size_t)16 * 8192);
    const short8 b2 = *reinterpret_cast<const short8*>(hbase + kk + (size_t)32 * 8192);
    const short8 b3 = *reinterpret_cast<const short8*>(hbase + kk + (size_t)48 * 8192);

    f32x4 pA, pB;
#pragma unroll
    for (int q = 0; q < 4; ++q) {
      const bool cA = (eA[q] >= TA);
      pA[q] = (cA ? E1zA : E01zA) * (cA ? eA[q] : fA[q]);
      const bool cB = (eA[q] >= TB);
      pB[q] = (cB ? E1zB : E01zB) * (cB ? eA[q] : fA[q]);
    }
    // att: 8 consecutive lanes cover 128 B contiguous of one row (full line)
    __builtin_nontemporal_store(pA, reinterpret_cast<f32x4*>(attA + kk));
    __builtin_nontemporal_store(pB, reinterpret_cast<f32x4*>(attB + kk));

    // bf16 halves -> A-frag positions
    uint2 uA, uB;
    uA.x = cvt_pk_bf16(pA[0], pA[1]); uA.y = cvt_pk_bf16(pA[2], pA[3]);
    uB.x = cvt_pk_bf16(pB[0], pB[1]); uB.y = cvt_pk_bf16(pB[2], pB[3]);
    *reinterpret_cast<uint2*>(plsb + par * 4096 + fragA) = uA;
    *reinterpret_cast<uint2*>(plsb + par * 4096 + fragB) = uB;

    // LDS handoff barrier WITHOUT vmcnt drain
    asm volatile("s_waitcnt lgkmcnt(0)\n\ts_barrier" ::: "memory");

    const short8* pbuf = reinterpret_cast<const short8*>(plsb + par * 4096);
    const short8 af0 = pbuf[0 * 64 + l];
    const short8 af1 = pbuf[1 * 64 + l];
    const short8 af2 = pbuf[2 * 64 + l];
    const short8 af3 = pbuf[3 * 64 + l];

    __builtin_amdgcn_s_setprio(1);
    acc[0][0] = __builtin_amdgcn_mfma_f32_16x16x32_bf16(af0, b0, acc[0][0], 0, 0, 0);
    acc[1][0] = __builtin_amdgcn_mfma_f32_16x16x32_bf16(af1, b0, acc[1][0], 0, 0, 0);
    acc[2][0] = __builtin_amdgcn_mfma_f32_16x16x32_bf16(af2, b0, acc[2][0], 0, 0, 0);
    acc[3][0] = __builtin_amdgcn_mfma_f32_16x16x32_bf16(af3, b0, acc[3][0], 0, 0, 0);
    acc[0][1] = __builtin_amdgcn_mfma_f32_16x16x32_bf16(af0, b1, acc[0][1], 0, 0, 0);
    acc[1][1] = __builtin_amdgcn_mfma_f32_16x16x32_bf16(af1, b1, acc[1][1], 0, 0, 0);
    acc[2][1] = __builtin_amdgcn_mfma_f32_16x16x32_bf16(af2, b1, acc[2][1], 0, 0, 0);
    acc[3][1] = __builtin_amdgcn_mfma_f32_16x16x32_bf16(af3, b1, acc[3][1], 0, 0, 0);
    acc[0][2] = __builtin_amdgcn_mfma_f32_16x16x32_bf16(af0, b2, acc[0][2], 0, 0, 0);
    acc[1][2] = __builtin_amdgcn_mfma_f32_16x16x32_bf16(af1, b2, acc[1][2], 0, 0, 0);
    acc[2][2] = __builtin_amdgcn_mfma_f32_16x16x32_bf16(af2, b2, acc[2][2], 0, 0, 0);
    acc[3][2] = __builtin_amdgcn_mfma_f32_16x16x32_bf16(af3, b2, acc[3][2], 0, 0, 0);
    acc[0][3] = __builtin_amdgcn_mfma_f32_16x16x32_bf16(af0, b3, acc[0][3], 0, 0, 0);
    acc[1][3] = __builtin_amdgcn_mfma_f32_16x16x32_bf16(af1, b3, acc[1][3], 0, 0, 0);
    acc[2][3] = __builtin_amdgcn_mfma_f32_16x16x32_bf16(af2, b3, acc[2][3], 0, 0, 0);
    acc[3][3] = __builtin_amdgcn_mfma_f32_16x16x32_bf16(af3, b3, acc[3][3], 0, 0, 0);
    __builtin_amdgcn_s_setprio(0);
  }

  // epilogue: raw partial sums, nontemporal (read once by k_reduce)
  float* pb = part + (size_t)blockIdx.y * ((size_t)NROW * DDIM);
#pragma unroll
  for (int rt = 0; rt < 4; ++rt)
#pragma unroll
    for (int ct = 0; ct < 4; ++ct)
#pragma unroll
      for (int q = 0; q < 4; ++q)
        __builtin_nontemporal_store(acc[rt][ct][q],
            pb + (size_t)(rb + rt * 16 + lg * 4 + q) * 256 + w * 64 + ct * 16 + lr);
}

// ---------------- K5: out = lrelu(sum_k part[k]) ----------------
__global__ __launch_bounds__(256) void k_reduce(
    const float* __restrict__ part, float* __restrict__ out, int KS)
{
  const size_t idx = ((size_t)blockIdx.x * 256 + threadIdx.x) * 4;
  f32x4 s = __builtin_nontemporal_load(reinterpret_cast<const f32x4*>(part + idx));
  for (int k = 1; k < KS; ++k) {
    const f32x4 v = __builtin_nontemporal_load(
        reinterpret_cast<const f32x4*>(part + (size_t)k * NROW * DDIM + idx));
#pragma unroll
    for (int q = 0; q < 4; ++q) s[q] += v[q];
  }
#pragma unroll
  for (int q = 0; q < 4; ++q) s[q] = lrelu(s[q]);
  __builtin_nontemporal_store(s, reinterpret_cast<f32x4*>(out + idx));
}

extern "C" void kernel_launch(void* const* d_in, const int* in_sizes, int n_in,
                              void* d_out, int out_size, void* d_ws, size_t ws_size,
                              hipStream_t stream)
{
  const float* doc = (const float*)d_in[0];
  const float* W   = (const float*)d_in[1];
  const float* Wb  = (const float*)d_in[2];
  const float* a   = (const float*)d_in[3];
  const float* ab  = (const float*)d_in[4];

  float* out = (float*)d_out;                 // 8192*256
  float* att = out + (size_t)8192 * 256;      // 8192*8192

  char* ws = (char*)d_ws;
  float* h           = (float*)ws;                                      // 8 MB
  unsigned short* ht = (unsigned short*)(ws + (size_t)8 * 1024 * 1024); // 4 MB
  char* tb           = ws + (size_t)12 * 1024 * 1024;
  float* s1  = (float*)tb;
  float* s2  = s1 + 8192;
  float* e2  = s2 + 8192;
  float* e02 = e2 + 8192;
  float* rowinfo = e02 + 8192;
  const size_t base = (size_t)12 * 1024 * 1024 + 288 * 1024;
  const size_t partBytes = (size_t)NROW * DDIM * sizeof(float);  // 8 MB per slice

  int KS = 1;
  for (int c = 8; c >= 1; c >>= 1)
    if (base + (size_t)c * partBytes <= ws_size) { KS = c; break; }
  float* part = (float*)(ws + base);
  const int CHUNK = NROW / KS;
  const size_t smem = 8192 + (size_t)2 * CHUNK * sizeof(float);

  hipLaunchKernelGGL(k_h,      dim3(4, 128),   dim3(256), 0,    stream, doc, W, Wb, h, ht);
  hipLaunchKernelGGL(k_s12,    dim3(256),      dim3(256), 0,    stream, h, a, s1, s2, e2, e02);
  hipLaunchKernelGGL(k_z,      dim3(512),      dim3(256), 0,    stream, s1, e2, e02, ab, rowinfo);
  hipLaunchKernelGGL(k_att,    dim3(128, KS),  dim3(256), smem, stream, rowinfo, e2, e02, ht, att, part, CHUNK);
  hipLaunchKernelGGL(k_reduce, dim3(2048),     dim3(256), 0,    stream, part, out, KS);
}

// Round 6
// 153.107 us; speedup vs baseline: 1.4089x; 1.3822x over previous
//
#include <hip/hip_runtime.h>
#include <hip/hip_bf16.h>

// GAT layer: h = doc@W + Wb; s1 = h@a1, s2 = h@a2;
// score[i,j] = lrelu(s1[i]+s2[j]+ab); att = softmax_rows(score); out = lrelu(att@h)
// N=8192, IN=512, D=256. Outputs: out (8192*256) then att (8192*8192), fp32.
//
// exp(lrelu(s1a+s2j)) = (s2j >= -s1a) ? exp(s1a)*e2[j] : exp(.1*s1a)*e02[j]
// with e2[j]=exp(s2[j]), e02[j]=exp(.1*s2[j]) -> no transcendentals in N^2 loops.

typedef __attribute__((ext_vector_type(4))) float f32x4;
typedef __attribute__((ext_vector_type(8))) short short8;
typedef __attribute__((ext_vector_type(4))) unsigned short ushort4v;

#define SLOPE 0.1f
#define NROW 8192
#define DDIM 256

__device__ __forceinline__ float lrelu(float x){ return fmaxf(x, SLOPE * x); }

// round-to-nearest-even fp32 -> bf16
__device__ __forceinline__ unsigned short f2bf(float f){
  union { float f; unsigned u; } v; v.f = f;
  unsigned r = (v.u + 0x7fffu + ((v.u >> 16) & 1u)) >> 16;
  return (unsigned short)r;
}

// two fp32 -> packed 2x bf16 (RNE), single HW instr
__device__ __forceinline__ unsigned cvt_pk_bf16(float lo, float hi){
  unsigned r;
  asm("v_cvt_pk_bf16_f32 %0, %1, %2" : "=v"(r) : "v"(lo), "v"(hi));
  return r;
}

// ---------------- K1: h = doc @ W + Wb (fp32) + ht = h^T bf16 ----------------
__global__ __launch_bounds__(256) void k_h(
    const float* __restrict__ doc, const float* __restrict__ W,
    const float* __restrict__ Wb, float* __restrict__ h,
    unsigned short* __restrict__ ht)
{
  __shared__ __align__(16) float At[16][68];
  __shared__ __align__(16) float Bs[16][68];
  const int t  = threadIdx.x;
  const int cb = blockIdx.x * 64;
  const int rb = blockIdx.y * 64;
  const int tx = t & 15, ty = t >> 4;

  float acc[4][4] = {};
  const int srow = t >> 2, skq = t & 3;
  const int bk = t >> 4, bc = t & 15;

  for (int kk = 0; kk < 512; kk += 16) {
    f32x4 av = *reinterpret_cast<const f32x4*>(doc + (size_t)(rb + srow) * 512 + kk + skq * 4);
    f32x4 wv = *reinterpret_cast<const f32x4*>(W + (size_t)(kk + bk) * 256 + cb + bc * 4);
    __syncthreads();
    At[skq * 4 + 0][srow] = av[0];
    At[skq * 4 + 1][srow] = av[1];
    At[skq * 4 + 2][srow] = av[2];
    At[skq * 4 + 3][srow] = av[3];
    *reinterpret_cast<f32x4*>(&Bs[bk][bc * 4]) = wv;
    __syncthreads();
#pragma unroll
    for (int k = 0; k < 16; ++k) {
      f32x4 a4 = *reinterpret_cast<const f32x4*>(&At[k][ty * 4]);
      f32x4 b4 = *reinterpret_cast<const f32x4*>(&Bs[k][tx * 4]);
#pragma unroll
      for (int i = 0; i < 4; ++i)
#pragma unroll
        for (int j = 0; j < 4; ++j)
          acc[i][j] = fmaf(a4[i], b4[j], acc[i][j]);
    }
  }

  float bias[4];
#pragma unroll
  for (int j = 0; j < 4; ++j) bias[j] = Wb[cb + tx * 4 + j];

#pragma unroll
  for (int i = 0; i < 4; ++i) {
    const int r = rb + ty * 4 + i;
    f32x4 o;
#pragma unroll
    for (int j = 0; j < 4; ++j) o[j] = acc[i][j] + bias[j];
    *reinterpret_cast<f32x4*>(h + (size_t)r * 256 + cb + tx * 4) = o;
  }
#pragma unroll
  for (int j = 0; j < 4; ++j) {
    const int c = cb + tx * 4 + j;
    ushort4v u;
#pragma unroll
    for (int i = 0; i < 4; ++i) u[i] = f2bf(acc[i][j] + bias[j]);
    *reinterpret_cast<ushort4v*>(ht + (size_t)c * 8192 + rb + ty * 4) = u;
  }
}

// ---------------- K2: s1,s2 + exp tables e2=exp(s2), e02=exp(.1*s2) ----------------
__global__ __launch_bounds__(256) void k_s12(
    const float* __restrict__ h, const float* __restrict__ a,
    float* __restrict__ s1, float* __restrict__ s2,
    float* __restrict__ e2, float* __restrict__ e02)
{
  const int t = threadIdx.x, w = t >> 6, l = t & 63;
  float a1[4], a2[4];
#pragma unroll
  for (int q = 0; q < 4; ++q) { a1[q] = a[l + q * 64]; a2[q] = a[256 + l + q * 64]; }
  const int rbase = blockIdx.x * 32 + w * 8;
  for (int rr = 0; rr < 8; ++rr) {
    const int r = rbase + rr;
    float v1 = 0.f, v2 = 0.f;
#pragma unroll
    for (int q = 0; q < 4; ++q) {
      float hv = h[(size_t)r * 256 + l + q * 64];
      v1 = fmaf(hv, a1[q], v1);
      v2 = fmaf(hv, a2[q], v2);
    }
#pragma unroll
    for (int off = 32; off > 0; off >>= 1) { v1 += __shfl_down(v1, off); v2 += __shfl_down(v2, off); }
    if (l == 0) {
      s1[r] = v1; s2[r] = v2;
      e2[r] = __expf(v2); e02[r] = __expf(SLOPE * v2);
    }
  }
}

// ---------------- K3: per-row Z -> rowinfo {E1*iz, E01*iz, T, iz} ----------------
// grid 512: 16 rows/block, 4 rows/wave; separate e2/e02 LDS arrays, contiguous
// f32x4 per lane (conflict-free b128), 4 rows share each e-read.
__global__ __launch_bounds__(256) void k_z(
    const float* __restrict__ s1, const float* __restrict__ e2g,
    const float* __restrict__ e02g, const float* __restrict__ abp,
    float* __restrict__ rowinfo)
{
  __shared__ __align__(16) float es[8192];
  __shared__ __align__(16) float fs[8192];
  const int t = threadIdx.x;
  for (int i = t * 4; i < 8192; i += 1024) {
    *reinterpret_cast<f32x4*>(&es[i]) = *reinterpret_cast<const f32x4*>(e2g + i);
    *reinterpret_cast<f32x4*>(&fs[i]) = *reinterpret_cast<const f32x4*>(e02g + i);
  }
  __syncthreads();
  const int w = t >> 6, l = t & 63;
  const float ab = abp[0];
  const int rb = blockIdx.x * 16 + w * 4;
  float T[4], E1[4], E01[4];
#pragma unroll
  for (int rr = 0; rr < 4; ++rr) {
    const float s1a = s1[rb + rr] + ab;
    E1[rr] = __expf(s1a); E01[rr] = __expf(SLOPE * s1a); T[rr] = __expf(-s1a);
  }
  float zA[4] = {0.f,0.f,0.f,0.f}, zB[4] = {0.f,0.f,0.f,0.f};
  for (int i = l * 4; i < 8192; i += 256) {
    const f32x4 e = *reinterpret_cast<const f32x4*>(&es[i]);
    const f32x4 f = *reinterpret_cast<const f32x4*>(&fs[i]);
#pragma unroll
    for (int rr = 0; rr < 4; ++rr)
#pragma unroll
      for (int q = 0; q < 4; ++q) {
        const bool c = (e[q] >= T[rr]);
        zA[rr] += c ? e[q] : 0.f;
        zB[rr] += c ? 0.f : f[q];
      }
  }
#pragma unroll
  for (int rr = 0; rr < 4; ++rr) {
    float z = E1[rr] * zA[rr] + E01[rr] * zB[rr];
#pragma unroll
    for (int off = 32; off > 0; off >>= 1) z += __shfl_down(z, off);
    if (l == 0) {
      const float iz = 1.0f / z;
      f32x4 ri = (f32x4){E1[rr] * iz, E01[rr] * iz, T[rr], iz};
      *reinterpret_cast<f32x4*>(rowinfo + (size_t)(rb + rr) * 4) = ri;
    }
  }
}

// ---------------- K4: att + partial out via MFMA, split-K, pipelined ----------------
// grid (KS, 128): x = k-slice (FASTEST -> one slice per XCD, ht slice L2-resident),
// y = row-block (64 rows). 4 waves, 32-k step, software-pipelined:
// region n: [ds_read frags(n) + b-loads(n) + MFMA(n)] || [gen p(n+1): e-LDS reads,
// VALU, att nt-store, cvt_pk, ds_write buf^1]. One lgkmcnt-only barrier per iter.
// Writer lanes (r8 = l>>3, jc = l&7): 8 lanes = 128 B contiguous per row.
__global__ __launch_bounds__(256, 4) void k_att(
    const float* __restrict__ rowinfo, const float* __restrict__ e2g,
    const float* __restrict__ e02g, const unsigned short* __restrict__ ht,
    float* __restrict__ att, float* __restrict__ part, int CHUNK)
{
  extern __shared__ __align__(16) char smem[];
  char* plsb  = smem;                                    // [2][4][64] short8 = 8 KB
  float* e2s  = reinterpret_cast<float*>(smem + 8192);   // CHUNK
  float* e02s = e2s + CHUNK;                             // CHUNK

  const int t = threadIdx.x, w = t >> 6, l = t & 63;
  const int lr = l & 15, lg = l >> 4;
  const int kbase = blockIdx.x * CHUNK;     // slice index (fastest -> XCD)
  const int rb = blockIdx.y * 64;

  for (int i = t * 4; i < CHUNK; i += 1024) {
    *reinterpret_cast<f32x4*>(e2s + i)  = *reinterpret_cast<const f32x4*>(e2g + kbase + i);
    *reinterpret_cast<f32x4*>(e02s + i) = *reinterpret_cast<const f32x4*>(e02g + kbase + i);
  }

  // ---- writer role ----
  const int r8 = l >> 3, jc = l & 7;
  const int rowA = rb + w * 16 + r8;
  const int rowB = rowA + 8;
  const f32x4 riA = *reinterpret_cast<const f32x4*>(rowinfo + (size_t)rowA * 4);
  const f32x4 riB = *reinterpret_cast<const f32x4*>(rowinfo + (size_t)rowB * 4);
  const float E1zA = riA[0], E01zA = riA[1], TA = riA[2];
  const float E1zB = riB[0], E01zB = riB[1], TB = riB[2];
  float* attA = att + (size_t)rowA * 8192 + kbase + jc * 4;
  float* attB = att + (size_t)rowB * 8192 + kbase + jc * 4;
  const int fragA = w * 1024 + ((jc >> 1) * 16 + r8) * 16 + (jc & 1) * 8;
  const int fragB = fragA + 128;

  __syncthreads();   // e2s/e02s staged (gen reads them)

  // gen: produce p for k-window kw, store att, write bf16 frags into buffer pb
  auto gen = [&](int kw, int pb) {
    const f32x4 eA = *reinterpret_cast<const f32x4*>(e2s + kw + jc * 4);
    const f32x4 fA = *reinterpret_cast<const f32x4*>(e02s + kw + jc * 4);
    f32x4 pA, pB;
#pragma unroll
    for (int q = 0; q < 4; ++q) {
      const bool cA = (eA[q] >= TA);
      pA[q] = (cA ? E1zA : E01zA) * (cA ? eA[q] : fA[q]);
      const bool cB = (eA[q] >= TB);
      pB[q] = (cB ? E1zB : E01zB) * (cB ? eA[q] : fA[q]);
    }
    __builtin_nontemporal_store(pA, reinterpret_cast<f32x4*>(attA + kw));
    __builtin_nontemporal_store(pB, reinterpret_cast<f32x4*>(attB + kw));
    uint2 uA, uB;
    uA.x = cvt_pk_bf16(pA[0], pA[1]); uA.y = cvt_pk_bf16(pA[2], pA[3]);
    uB.x = cvt_pk_bf16(pB[0], pB[1]); uB.y = cvt_pk_bf16(pB[2], pB[3]);
    *reinterpret_cast<uint2*>(plsb + pb * 4096 + fragA) = uA;
    *reinterpret_cast<uint2*>(plsb + pb * 4096 + fragB) = uB;
  };

  f32x4 acc[4][4];
#pragma unroll
  for (int rt = 0; rt < 4; ++rt)
#pragma unroll
    for (int ct = 0; ct < 4; ++ct) acc[rt][ct] = (f32x4){0.f, 0.f, 0.f, 0.f};

  const unsigned short* hbase = ht + (size_t)(w * 64 + lr) * 8192 + kbase + lg * 8;

  gen(0, 0);   // prologue: window 0 into buffer 0

  const int NIT = CHUNK / 32;
  for (int n = 0; n < NIT; ++n) {
    const int kk = n * 32;
    const int par = n & 1;

    // frag handoff barrier WITHOUT vmcnt drain (att nt-stores stay in flight)
    asm volatile("s_waitcnt lgkmcnt(0)\n\ts_barrier" ::: "memory");

    // B fragments for this window (L2-resident ht slice)
    const short8 b0 = *reinterpret_cast<const short8*>(hbase + kk);
    const short8 b1 = *reinterpret_cast<const short8*>(hbase + kk + (size_t)16 * 8192);
    const short8 b2 = *reinterpret_cast<const short8*>(hbase + kk + (size_t)32 * 8192);
    const short8 b3 = *reinterpret_cast<const short8*>(hbase + kk + (size_t)48 * 8192);

    // A fragments for this window
    const short8* pbuf = reinterpret_cast<const short8*>(plsb + par * 4096);
    const short8 af0 = pbuf[0 * 64 + l];
    const short8 af1 = pbuf[1 * 64 + l];
    const short8 af2 = pbuf[2 * 64 + l];
    const short8 af3 = pbuf[3 * 64 + l];

    // generate NEXT window into the other buffer (overlaps with MFMA below)
    if (n + 1 < NIT) gen(kk + 32, par ^ 1);

    __builtin_amdgcn_s_setprio(1);
    acc[0][0] = __builtin_amdgcn_mfma_f32_16x16x32_bf16(af0, b0, acc[0][0], 0, 0, 0);
    acc[1][0] = __builtin_amdgcn_mfma_f32_16x16x32_bf16(af1, b0, acc[1][0], 0, 0, 0);
    acc[2][0] = __builtin_amdgcn_mfma_f32_16x16x32_bf16(af2, b0, acc[2][0], 0, 0, 0);
    acc[3][0] = __builtin_amdgcn_mfma_f32_16x16x32_bf16(af3, b0, acc[3][0], 0, 0, 0);
    acc[0][1] = __builtin_amdgcn_mfma_f32_16x16x32_bf16(af0, b1, acc[0][1], 0, 0, 0);
    acc[1][1] = __builtin_amdgcn_mfma_f32_16x16x32_bf16(af1, b1, acc[1][1], 0, 0, 0);
    acc[2][1] = __builtin_amdgcn_mfma_f32_16x16x32_bf16(af2, b1, acc[2][1], 0, 0, 0);
    acc[3][1] = __builtin_amdgcn_mfma_f32_16x16x32_bf16(af3, b1, acc[3][1], 0, 0, 0);
    acc[0][2] = __builtin_amdgcn_mfma_f32_16x16x32_bf16(af0, b2, acc[0][2], 0, 0, 0);
    acc[1][2] = __builtin_amdgcn_mfma_f32_16x16x32_bf16(af1, b2, acc[1][2], 0, 0, 0);
    acc[2][2] = __builtin_amdgcn_mfma_f32_16x16x32_bf16(af2, b2, acc[2][2], 0, 0, 0);
    acc[3][2] = __builtin_amdgcn_mfma_f32_16x16x32_bf16(af3, b2, acc[3][2], 0, 0, 0);
    acc[0][3] = __builtin_amdgcn_mfma_f32_16x16x32_bf16(af0, b3, acc[0][3], 0, 0, 0);
    acc[1][3] = __builtin_amdgcn_mfma_f32_16x16x32_bf16(af1, b3, acc[1][3], 0, 0, 0);
    acc[2][3] = __builtin_amdgcn_mfma_f32_16x16x32_bf16(af2, b3, acc[2][3], 0, 0, 0);
    acc[3][3] = __builtin_amdgcn_mfma_f32_16x16x32_bf16(af3, b3, acc[3][3], 0, 0, 0);
    __builtin_amdgcn_s_setprio(0);
  }

  // epilogue: raw partial sums, nontemporal (read once by k_reduce)
  float* pb = part + (size_t)blockIdx.x * ((size_t)NROW * DDIM);
#pragma unroll
  for (int rt = 0; rt < 4; ++rt)
#pragma unroll
    for (int ct = 0; ct < 4; ++ct)
#pragma unroll
      for (int q = 0; q < 4; ++q)
        __builtin_nontemporal_store(acc[rt][ct][q],
            pb + (size_t)(rb + rt * 16 + lg * 4 + q) * 256 + w * 64 + ct * 16 + lr);
}

// ---------------- K5: out = lrelu(sum_k part[k]) ----------------
__global__ __launch_bounds__(256) void k_reduce(
    const float* __restrict__ part, float* __restrict__ out, int KS)
{
  const size_t idx = ((size_t)blockIdx.x * 256 + threadIdx.x) * 4;
  f32x4 s = __builtin_nontemporal_load(reinterpret_cast<const f32x4*>(part + idx));
  for (int k = 1; k < KS; ++k) {
    const f32x4 v = __builtin_nontemporal_load(
        reinterpret_cast<const f32x4*>(part + (size_t)k * NROW * DDIM + idx));
#pragma unroll
    for (int q = 0; q < 4; ++q) s[q] += v[q];
  }
#pragma unroll
  for (int q = 0; q < 4; ++q) s[q] = lrelu(s[q]);
  __builtin_nontemporal_store(s, reinterpret_cast<f32x4*>(out + idx));
}

extern "C" void kernel_launch(void* const* d_in, const int* in_sizes, int n_in,
                              void* d_out, int out_size, void* d_ws, size_t ws_size,
                              hipStream_t stream)
{
  const float* doc = (const float*)d_in[0];
  const float* W   = (const float*)d_in[1];
  const float* Wb  = (const float*)d_in[2];
  const float* a   = (const float*)d_in[3];
  const float* ab  = (const float*)d_in[4];

  float* out = (float*)d_out;                 // 8192*256
  float* att = out + (size_t)8192 * 256;      // 8192*8192

  char* ws = (char*)d_ws;
  float* h           = (float*)ws;                                      // 8 MB
  unsigned short* ht = (unsigned short*)(ws + (size_t)8 * 1024 * 1024); // 4 MB
  char* tb           = ws + (size_t)12 * 1024 * 1024;
  float* s1  = (float*)tb;
  float* s2  = s1 + 8192;
  float* e2  = s2 + 8192;
  float* e02 = e2 + 8192;
  float* rowinfo = e02 + 8192;
  const size_t base = (size_t)12 * 1024 * 1024 + 288 * 1024;
  const size_t partBytes = (size_t)NROW * DDIM * sizeof(float);  // 8 MB per slice

  int KS = 1;
  for (int c = 8; c >= 1; c >>= 1)
    if (base + (size_t)c * partBytes <= ws_size) { KS = c; break; }
  float* part = (float*)(ws + base);
  const int CHUNK = NROW / KS;
  const size_t smem = 8192 + (size_t)2 * CHUNK * sizeof(float);

  hipLaunchKernelGGL(k_h,      dim3(4, 128),   dim3(256), 0,    stream, doc, W, Wb, h, ht);
  hipLaunchKernelGGL(k_s12,    dim3(256),      dim3(256), 0,    stream, h, a, s1, s2, e2, e02);
  hipLaunchKernelGGL(k_z,      dim3(512),      dim3(256), 0,    stream, s1, e2, e02, ab, rowinfo);
  hipLaunchKernelGGL(k_att,    dim3(KS, 128),  dim3(256), smem, stream, rowinfo, e2, e02, ht, att, part, CHUNK);
  hipLaunchKernelGGL(k_reduce, dim3(2048),     dim3(256), 0,    stream, part, out, KS);
}

// Round 7
// 145.730 us; speedup vs baseline: 1.4802x; 1.0506x over previous
//
#include <hip/hip_runtime.h>
#include <hip/hip_bf16.h>

// GAT layer: h = doc@W + Wb; s1 = h@a1, s2 = h@a2;
// score[i,j] = lrelu(s1[i]+s2[j]+ab); att = softmax_rows(score); out = lrelu(att@h)
// N=8192, IN=512, D=256. Outputs: out (8192*256) then att (8192*8192), fp32.
//
// exp(lrelu(s1a+s2j)) = (s2j >= -s1a) ? exp(s1a)*e2[j] : exp(.1*s1a)*e02[j]
// -> no transcendentals in N^2 loops.
// h computed via bf16-split MFMA: x = hi+lo; hi*hi + hi*lo + lo*hi ~ fp32 (2^-17 rel).

typedef __attribute__((ext_vector_type(4))) float f32x4;
typedef __attribute__((ext_vector_type(8))) short short8;
typedef __attribute__((ext_vector_type(4))) unsigned short ushort4v;

#define SLOPE 0.1f
#define NROW 8192
#define DDIM 256

__device__ __forceinline__ float lrelu(float x){ return fmaxf(x, SLOPE * x); }

// round-to-nearest-even fp32 -> bf16
__device__ __forceinline__ unsigned short f2bf(float f){
  union { float f; unsigned u; } v; v.f = f;
  unsigned r = (v.u + 0x7fffu + ((v.u >> 16) & 1u)) >> 16;
  return (unsigned short)r;
}
__device__ __forceinline__ float bf2f(unsigned short u){
  union { unsigned u; float f; } v; v.u = (unsigned)u << 16; return v.f;
}
// two fp32 -> packed 2x bf16 (RNE), single HW instr
__device__ __forceinline__ unsigned cvt_pk_bf16(float lo, float hi){
  unsigned r;
  asm("v_cvt_pk_bf16_f32 %0, %1, %2" : "=v"(r) : "v"(lo), "v"(hi));
  return r;
}

// ---------------- K0: Wt_hi/Wt_lo [256][512] bf16 split-transpose of W [512][256] ----------------
__global__ __launch_bounds__(256) void k_prep(
    const float* __restrict__ W,
    unsigned short* __restrict__ Wt_hi, unsigned short* __restrict__ Wt_lo)
{
  const int tid = blockIdx.x * 256 + threadIdx.x;   // 32768 total
  const int c = tid >> 7, kq = tid & 127;
  ushort4v hi, lo;
#pragma unroll
  for (int j = 0; j < 4; ++j) {
    const float v = W[(size_t)(kq * 4 + j) * 256 + c];
    hi[j] = f2bf(v);
    lo[j] = f2bf(v - bf2f(hi[j]));
  }
  *reinterpret_cast<ushort4v*>(Wt_hi + (size_t)c * 512 + kq * 4) = hi;
  *reinterpret_cast<ushort4v*>(Wt_lo + (size_t)c * 512 + kq * 4) = lo;
}

// ---------------- K1: h-tile via split MFMA; fused s1/s2/e2/e02 + ht bf16 ----------------
// grid 256: block = 32 rows x 256 cols, 4 waves; wave w owns cols w*64..+63.
// Waves 0,1 stage A-frags (doc rows, hi/lo split) into LDS; K-loop 16x32.
// Epilogue: ht writes + per-row s1/s2 (cross-wave LDS reduce) + e2/e02.
__global__ __launch_bounds__(256) void k_h(
    const float* __restrict__ doc, const unsigned short* __restrict__ Wt_hi,
    const unsigned short* __restrict__ Wt_lo, const float* __restrict__ Wb,
    const float* __restrict__ a,
    unsigned short* __restrict__ ht, float* __restrict__ s1,
    float* __restrict__ e2, float* __restrict__ e02)
{
  __shared__ __align__(16) short8 aH[2][2][64];   // [buf][rt][lane] 4 KB
  __shared__ __align__(16) short8 aL[2][2][64];   // 4 KB
  __shared__ float sred[4][2][32];                // 1 KB

  const int t = threadIdx.x, w = t >> 6, l = t & 63;
  const int lr = l & 15, lg = l >> 4;
  const int rb = blockIdx.x * 32;
  const int cb = w * 64;

  f32x4 acc[2][4];
#pragma unroll
  for (int rt = 0; rt < 2; ++rt)
#pragma unroll
    for (int ct = 0; ct < 4; ++ct) acc[rt][ct] = (f32x4){0.f, 0.f, 0.f, 0.f};

  const float* docp = doc + (size_t)(rb + w * 16 + lr) * 512 + lg * 8;  // valid for w<2

  f32x4 v0, v1;   // doc prefetch regs (window n+1)
  auto loadDoc = [&](int k0) { if (w < 2) {
      v0 = *reinterpret_cast<const f32x4*>(docp + k0);
      v1 = *reinterpret_cast<const f32x4*>(docp + k0 + 4);
  }};
  auto writeStage = [&](int pb) { if (w < 2) {
      union { short8 v; unsigned short u[8]; } hi, lo;
#pragma unroll
      for (int q = 0; q < 4; ++q) {
        hi.u[q] = f2bf(v0[q]);     lo.u[q] = f2bf(v0[q] - bf2f(hi.u[q]));
        hi.u[4+q] = f2bf(v1[q]);   lo.u[4+q] = f2bf(v1[q] - bf2f(hi.u[4+q]));
      }
      aH[pb][w][l] = hi.v;
      aL[pb][w][l] = lo.v;
  }};

  loadDoc(0); writeStage(0); loadDoc(32);

  for (int n = 0; n < 16; ++n) {
    const int kk = n * 32;
    const int par = n & 1;

    asm volatile("s_waitcnt lgkmcnt(0)\n\ts_barrier" ::: "memory");

    const short8 ah0 = aH[par][0][l];
    const short8 ah1 = aH[par][1][l];
    const short8 al0 = aL[par][0][l];
    const short8 al1 = aL[par][1][l];

    short8 bh[4], bl[4];
#pragma unroll
    for (int ct = 0; ct < 4; ++ct) {
      const size_t off = (size_t)(cb + ct * 16 + lr) * 512 + kk + lg * 8;
      bh[ct] = *reinterpret_cast<const short8*>(Wt_hi + off);
      bl[ct] = *reinterpret_cast<const short8*>(Wt_lo + off);
    }

    if (n + 1 < 16) writeStage(par ^ 1);
    if (n + 2 < 16) loadDoc((n + 2) * 32);

#pragma unroll
    for (int ct = 0; ct < 4; ++ct) {
      acc[0][ct] = __builtin_amdgcn_mfma_f32_16x16x32_bf16(ah0, bh[ct], acc[0][ct], 0, 0, 0);
      acc[1][ct] = __builtin_amdgcn_mfma_f32_16x16x32_bf16(ah1, bh[ct], acc[1][ct], 0, 0, 0);
      acc[0][ct] = __builtin_amdgcn_mfma_f32_16x16x32_bf16(ah0, bl[ct], acc[0][ct], 0, 0, 0);
      acc[1][ct] = __builtin_amdgcn_mfma_f32_16x16x32_bf16(ah1, bl[ct], acc[1][ct], 0, 0, 0);
      acc[0][ct] = __builtin_amdgcn_mfma_f32_16x16x32_bf16(al0, bh[ct], acc[0][ct], 0, 0, 0);
      acc[1][ct] = __builtin_amdgcn_mfma_f32_16x16x32_bf16(al1, bh[ct], acc[1][ct], 0, 0, 0);
    }
  }

  // bias add + ht write (C/D layout: col = cb+ct*16+lr, row = rb+rt*16+lg*4+q)
  float bias[4];
#pragma unroll
  for (int ct = 0; ct < 4; ++ct) bias[ct] = Wb[cb + ct * 16 + lr];
#pragma unroll
  for (int rt = 0; rt < 2; ++rt)
#pragma unroll
    for (int ct = 0; ct < 4; ++ct) {
#pragma unroll
      for (int q = 0; q < 4; ++q) acc[rt][ct][q] += bias[ct];
      ushort4v u;
#pragma unroll
      for (int q = 0; q < 4; ++q) u[q] = f2bf(acc[rt][ct][q]);
      *reinterpret_cast<ushort4v*>(
          ht + (size_t)(cb + ct * 16 + lr) * 8192 + rb + rt * 16 + lg * 4) = u;
    }

  // s1/s2: per-row dot with a1/a2 (this wave's 64 cols), reduce over lr, then waves
  float a1c[4], a2c[4];
#pragma unroll
  for (int ct = 0; ct < 4; ++ct) {
    a1c[ct] = a[cb + ct * 16 + lr];
    a2c[ct] = a[256 + cb + ct * 16 + lr];
  }
  float p1[2][4], p2[2][4];
#pragma unroll
  for (int rt = 0; rt < 2; ++rt)
#pragma unroll
    for (int q = 0; q < 4; ++q) {
      float x1 = 0.f, x2 = 0.f;
#pragma unroll
      for (int ct = 0; ct < 4; ++ct) {
        x1 = fmaf(acc[rt][ct][q], a1c[ct], x1);
        x2 = fmaf(acc[rt][ct][q], a2c[ct], x2);
      }
#pragma unroll
      for (int off = 1; off < 16; off <<= 1) {
        x1 += __shfl_xor(x1, off);
        x2 += __shfl_xor(x2, off);
      }
      p1[rt][q] = x1; p2[rt][q] = x2;
    }
  __syncthreads();   // A-staging LDS done; safe to write sred region
  if (lr == 0) {
#pragma unroll
    for (int rt = 0; rt < 2; ++rt)
#pragma unroll
      for (int q = 0; q < 4; ++q) {
        sred[w][0][rt * 16 + lg * 4 + q] = p1[rt][q];
        sred[w][1][rt * 16 + lg * 4 + q] = p2[rt][q];
      }
  }
  __syncthreads();
  if (t < 32) {
    float v1s = 0.f, v2s = 0.f;
#pragma unroll
    for (int ww = 0; ww < 4; ++ww) { v1s += sred[ww][0][t]; v2s += sred[ww][1][t]; }
    const int r = rb + t;
    s1[r] = v1s;
    e2[r] = __expf(v2s);
    e02[r] = __expf(SLOPE * v2s);
  }
}

// ---------------- K3: per-row Z -> rowinfo {E1*iz, E01*iz, T, iz} ----------------
__global__ __launch_bounds__(256) void k_z(
    const float* __restrict__ s1, const float* __restrict__ e2g,
    const float* __restrict__ e02g, const float* __restrict__ abp,
    float* __restrict__ rowinfo)
{
  __shared__ __align__(16) float es[8192];
  __shared__ __align__(16) float fs[8192];
  const int t = threadIdx.x;
  for (int i = t * 4; i < 8192; i += 1024) {
    *reinterpret_cast<f32x4*>(&es[i]) = *reinterpret_cast<const f32x4*>(e2g + i);
    *reinterpret_cast<f32x4*>(&fs[i]) = *reinterpret_cast<const f32x4*>(e02g + i);
  }
  __syncthreads();
  const int w = t >> 6, l = t & 63;
  const float ab = abp[0];
  const int rb = blockIdx.x * 16 + w * 4;
  float T[4], E1[4], E01[4];
#pragma unroll
  for (int rr = 0; rr < 4; ++rr) {
    const float s1a = s1[rb + rr] + ab;
    E1[rr] = __expf(s1a); E01[rr] = __expf(SLOPE * s1a); T[rr] = __expf(-s1a);
  }
  float zA[4] = {0.f,0.f,0.f,0.f}, zB[4] = {0.f,0.f,0.f,0.f};
  for (int i = l * 4; i < 8192; i += 256) {
    const f32x4 e = *reinterpret_cast<const f32x4*>(&es[i]);
    const f32x4 f = *reinterpret_cast<const f32x4*>(&fs[i]);
#pragma unroll
    for (int rr = 0; rr < 4; ++rr)
#pragma unroll
      for (int q = 0; q < 4; ++q) {
        const bool c = (e[q] >= T[rr]);
        zA[rr] += c ? e[q] : 0.f;
        zB[rr] += c ? 0.f : f[q];
      }
  }
#pragma unroll
  for (int rr = 0; rr < 4; ++rr) {
    float z = E1[rr] * zA[rr] + E01[rr] * zB[rr];
#pragma unroll
    for (int off = 32; off > 0; off >>= 1) z += __shfl_down(z, off);
    if (l == 0) {
      const float iz = 1.0f / z;
      f32x4 ri = (f32x4){E1[rr] * iz, E01[rr] * iz, T[rr], iz};
      *reinterpret_cast<f32x4*>(rowinfo + (size_t)(rb + rr) * 4) = ri;
    }
  }
}

// ---------------- K4: att + partial out via MFMA, split-K, pipelined ----------------
// grid (KS, 128): x = k-slice (fastest -> XCD-aligned L2 ht slice), y = 64-row block.
// 4 waves, 32-k step, software-pipelined gen(n+1) || MFMA(n), lgkm-only barrier.
__global__ __launch_bounds__(256, 4) void k_att(
    const float* __restrict__ rowinfo, const float* __restrict__ e2g,
    const float* __restrict__ e02g, const unsigned short* __restrict__ ht,
    float* __restrict__ att, float* __restrict__ part, int CHUNK)
{
  extern __shared__ __align__(16) char smem[];
  char* plsb  = smem;                                    // [2][4][64] short8 = 8 KB
  float* e2s  = reinterpret_cast<float*>(smem + 8192);   // CHUNK
  float* e02s = e2s + CHUNK;                             // CHUNK

  const int t = threadIdx.x, w = t >> 6, l = t & 63;
  const int lr = l & 15, lg = l >> 4;
  const int kbase = blockIdx.x * CHUNK;     // slice (fastest -> XCD)
  const int rb = blockIdx.y * 64;

  for (int i = t * 4; i < CHUNK; i += 1024) {
    *reinterpret_cast<f32x4*>(e2s + i)  = *reinterpret_cast<const f32x4*>(e2g + kbase + i);
    *reinterpret_cast<f32x4*>(e02s + i) = *reinterpret_cast<const f32x4*>(e02g + kbase + i);
  }

  // ---- writer role ----
  const int r8 = l >> 3, jc = l & 7;
  const int rowA = rb + w * 16 + r8;
  const int rowB = rowA + 8;
  const f32x4 riA = *reinterpret_cast<const f32x4*>(rowinfo + (size_t)rowA * 4);
  const f32x4 riB = *reinterpret_cast<const f32x4*>(rowinfo + (size_t)rowB * 4);
  const float E1zA = riA[0], E01zA = riA[1], TA = riA[2];
  const float E1zB = riB[0], E01zB = riB[1], TB = riB[2];
  float* attA = att + (size_t)rowA * 8192 + kbase + jc * 4;
  float* attB = att + (size_t)rowB * 8192 + kbase + jc * 4;
  const int fragA = w * 1024 + ((jc >> 1) * 16 + r8) * 16 + (jc & 1) * 8;
  const int fragB = fragA + 128;

  __syncthreads();

  auto gen = [&](int kw, int pb) {
    const f32x4 eA = *reinterpret_cast<const f32x4*>(e2s + kw + jc * 4);
    const f32x4 fA = *reinterpret_cast<const f32x4*>(e02s + kw + jc * 4);
    f32x4 pA, pB;
#pragma unroll
    for (int q = 0; q < 4; ++q) {
      const bool cA = (eA[q] >= TA);
      pA[q] = (cA ? E1zA : E01zA) * (cA ? eA[q] : fA[q]);
      const bool cB = (eA[q] >= TB);
      pB[q] = (cB ? E1zB : E01zB) * (cB ? eA[q] : fA[q]);
    }
    __builtin_nontemporal_store(pA, reinterpret_cast<f32x4*>(attA + kw));
    __builtin_nontemporal_store(pB, reinterpret_cast<f32x4*>(attB + kw));
    uint2 uA, uB;
    uA.x = cvt_pk_bf16(pA[0], pA[1]); uA.y = cvt_pk_bf16(pA[2], pA[3]);
    uB.x = cvt_pk_bf16(pB[0], pB[1]); uB.y = cvt_pk_bf16(pB[2], pB[3]);
    *reinterpret_cast<uint2*>(plsb + pb * 4096 + fragA) = uA;
    *reinterpret_cast<uint2*>(plsb + pb * 4096 + fragB) = uB;
  };

  f32x4 acc[4][4];
#pragma unroll
  for (int rt = 0; rt < 4; ++rt)
#pragma unroll
    for (int ct = 0; ct < 4; ++ct) acc[rt][ct] = (f32x4){0.f, 0.f, 0.f, 0.f};

  const unsigned short* hbase = ht + (size_t)(w * 64 + lr) * 8192 + kbase + lg * 8;

  gen(0, 0);

  const int NIT = CHUNK / 32;
  for (int n = 0; n < NIT; ++n) {
    const int kk = n * 32;
    const int par = n & 1;

    asm volatile("s_waitcnt lgkmcnt(0)\n\ts_barrier" ::: "memory");

    const short8 b0 = *reinterpret_cast<const short8*>(hbase + kk);
    const short8 b1 = *reinterpret_cast<const short8*>(hbase + kk + (size_t)16 * 8192);
    const short8 b2 = *reinterpret_cast<const short8*>(hbase + kk + (size_t)32 * 8192);
    const short8 b3 = *reinterpret_cast<const short8*>(hbase + kk + (size_t)48 * 8192);

    const short8* pbuf = reinterpret_cast<const short8*>(plsb + par * 4096);
    const short8 af0 = pbuf[0 * 64 + l];
    const short8 af1 = pbuf[1 * 64 + l];
    const short8 af2 = pbuf[2 * 64 + l];
    const short8 af3 = pbuf[3 * 64 + l];

    if (n + 1 < NIT) gen(kk + 32, par ^ 1);

    __builtin_amdgcn_s_setprio(1);
    acc[0][0] = __builtin_amdgcn_mfma_f32_16x16x32_bf16(af0, b0, acc[0][0], 0, 0, 0);
    acc[1][0] = __builtin_amdgcn_mfma_f32_16x16x32_bf16(af1, b0, acc[1][0], 0, 0, 0);
    acc[2][0] = __builtin_amdgcn_mfma_f32_16x16x32_bf16(af2, b0, acc[2][0], 0, 0, 0);
    acc[3][0] = __builtin_amdgcn_mfma_f32_16x16x32_bf16(af3, b0, acc[3][0], 0, 0, 0);
    acc[0][1] = __builtin_amdgcn_mfma_f32_16x16x32_bf16(af0, b1, acc[0][1], 0, 0, 0);
    acc[1][1] = __builtin_amdgcn_mfma_f32_16x16x32_bf16(af1, b1, acc[1][1], 0, 0, 0);
    acc[2][1] = __builtin_amdgcn_mfma_f32_16x16x32_bf16(af2, b1, acc[2][1], 0, 0, 0);
    acc[3][1] = __builtin_amdgcn_mfma_f32_16x16x32_bf16(af3, b1, acc[3][1], 0, 0, 0);
    acc[0][2] = __builtin_amdgcn_mfma_f32_16x16x32_bf16(af0, b2, acc[0][2], 0, 0, 0);
    acc[1][2] = __builtin_amdgcn_mfma_f32_16x16x32_bf16(af1, b2, acc[1][2], 0, 0, 0);
    acc[2][2] = __builtin_amdgcn_mfma_f32_16x16x32_bf16(af2, b2, acc[2][2], 0, 0, 0);
    acc[3][2] = __builtin_amdgcn_mfma_f32_16x16x32_bf16(af3, b2, acc[3][2], 0, 0, 0);
    acc[0][3] = __builtin_amdgcn_mfma_f32_16x16x32_bf16(af0, b3, acc[0][3], 0, 0, 0);
    acc[1][3] = __builtin_amdgcn_mfma_f32_16x16x32_bf16(af1, b3, acc[1][3], 0, 0, 0);
    acc[2][3] = __builtin_amdgcn_mfma_f32_16x16x32_bf16(af2, b3, acc[2][3], 0, 0, 0);
    acc[3][3] = __builtin_amdgcn_mfma_f32_16x16x32_bf16(af3, b3, acc[3][3], 0, 0, 0);
    __builtin_amdgcn_s_setprio(0);
  }

  float* pb = part + (size_t)blockIdx.x * ((size_t)NROW * DDIM);
#pragma unroll
  for (int rt = 0; rt < 4; ++rt)
#pragma unroll
    for (int ct = 0; ct < 4; ++ct)
#pragma unroll
      for (int q = 0; q < 4; ++q)
        __builtin_nontemporal_store(acc[rt][ct][q],
            pb + (size_t)(rb + rt * 16 + lg * 4 + q) * 256 + w * 64 + ct * 16 + lr);
}

// ---------------- K5: out = lrelu(sum_k part[k]) ----------------
__global__ __launch_bounds__(256) void k_reduce(
    const float* __restrict__ part, float* __restrict__ out, int KS)
{
  const size_t idx = ((size_t)blockIdx.x * 256 + threadIdx.x) * 4;
  f32x4 s = __builtin_nontemporal_load(reinterpret_cast<const f32x4*>(part + idx));
  for (int k = 1; k < KS; ++k) {
    const f32x4 v = __builtin_nontemporal_load(
        reinterpret_cast<const f32x4*>(part + (size_t)k * NROW * DDIM + idx));
#pragma unroll
    for (int q = 0; q < 4; ++q) s[q] += v[q];
  }
#pragma unroll
  for (int q = 0; q < 4; ++q) s[q] = lrelu(s[q]);
  __builtin_nontemporal_store(s, reinterpret_cast<f32x4*>(out + idx));
}

extern "C" void kernel_launch(void* const* d_in, const int* in_sizes, int n_in,
                              void* d_out, int out_size, void* d_ws, size_t ws_size,
                              hipStream_t stream)
{
  const float* doc = (const float*)d_in[0];
  const float* W   = (const float*)d_in[1];
  const float* Wb  = (const float*)d_in[2];
  const float* a   = (const float*)d_in[3];
  const float* ab  = (const float*)d_in[4];

  float* out = (float*)d_out;                 // 8192*256
  float* att = out + (size_t)8192 * 256;      // 8192*8192

  char* ws = (char*)d_ws;
  unsigned short* ht    = (unsigned short*)ws;                              // 4 MB
  unsigned short* Wt_hi = (unsigned short*)(ws + (size_t)4 * 1024 * 1024);  // 256 KB
  unsigned short* Wt_lo = Wt_hi + (size_t)256 * 512;                        // 256 KB
  float* s1      = (float*)(ws + (size_t)4 * 1024 * 1024 + 512 * 1024);     // 32 KB
  float* e2      = s1 + 8192;
  float* e02     = e2 + 8192;
  float* rowinfo = e02 + 8192;                                              // 128 KB
  const size_t base = (size_t)5 * 1024 * 1024;
  const size_t partBytes = (size_t)NROW * DDIM * sizeof(float);             // 8 MB

  int KS = 1;
  for (int c = 4; c >= 1; c >>= 1)
    if (base + (size_t)c * partBytes <= ws_size) { KS = c; break; }
  float* part = (float*)(ws + base);
  const int CHUNK = NROW / KS;
  const size_t smem = 8192 + (size_t)2 * CHUNK * sizeof(float);

  hipLaunchKernelGGL(k_prep,   dim3(128),     dim3(256), 0,    stream, W, Wt_hi, Wt_lo);
  hipLaunchKernelGGL(k_h,      dim3(256),     dim3(256), 0,    stream, doc, Wt_hi, Wt_lo, Wb, a, ht, s1, e2, e02);
  hipLaunchKernelGGL(k_z,      dim3(512),     dim3(256), 0,    stream, s1, e2, e02, ab, rowinfo);
  hipLaunchKernelGGL(k_att,    dim3(KS, 128), dim3(256), smem, stream, rowinfo, e2, e02, ht, att, part, CHUNK);
  hipLaunchKernelGGL(k_reduce, dim3(2048),    dim3(256), 0,    stream, part, out, KS);
}

// Round 8
// 132.489 us; speedup vs baseline: 1.6282x; 1.0999x over previous
//
#include <hip/hip_runtime.h>
#include <hip/hip_bf16.h>

// GAT layer: h = doc@W + Wb; s1 = h@a1, s2 = h@a2;
// score[i,j] = lrelu(s1[i]+s2[j]+ab); att = softmax_rows(score); out = lrelu(att@h)
// N=8192, IN=512, D=256. Outputs: out (8192*256) then att (8192*8192), fp32.
//
// exp(lrelu(s1a+s2j)) = (s2j >= -s1a) ? exp(s1a)*e2[j] : exp(.1*s1a)*e02[j]
// -> no transcendentals in N^2 loops.
// h computed via bf16-split MFMA: x = hi+lo; hi*hi + hi*lo + lo*hi ~ fp32 (2^-17 rel).

typedef __attribute__((ext_vector_type(4))) float f32x4;
typedef __attribute__((ext_vector_type(8))) short short8;
typedef __attribute__((ext_vector_type(4))) unsigned short ushort4v;

#define SLOPE 0.1f
#define NROW 8192
#define DDIM 256

__device__ __forceinline__ float lrelu(float x){ return fmaxf(x, SLOPE * x); }

// round-to-nearest-even fp32 -> bf16
__device__ __forceinline__ unsigned short f2bf(float f){
  union { float f; unsigned u; } v; v.f = f;
  unsigned r = (v.u + 0x7fffu + ((v.u >> 16) & 1u)) >> 16;
  return (unsigned short)r;
}
__device__ __forceinline__ float bf2f(unsigned short u){
  union { unsigned u; float f; } v; v.u = (unsigned)u << 16; return v.f;
}
// two fp32 -> packed 2x bf16 (RNE), single HW instr
__device__ __forceinline__ unsigned cvt_pk_bf16(float lo, float hi){
  unsigned r;
  asm("v_cvt_pk_bf16_f32 %0, %1, %2" : "=v"(r) : "v"(lo), "v"(hi));
  return r;
}

// ---------------- K0: Wt_hi/Wt_lo [256][512] bf16 split-transpose of W [512][256] ----------------
__global__ __launch_bounds__(256) void k_prep(
    const float* __restrict__ W,
    unsigned short* __restrict__ Wt_hi, unsigned short* __restrict__ Wt_lo)
{
  const int tid = blockIdx.x * 256 + threadIdx.x;   // 32768 total
  const int c = tid >> 7, kq = tid & 127;
  ushort4v hi, lo;
#pragma unroll
  for (int j = 0; j < 4; ++j) {
    const float v = W[(size_t)(kq * 4 + j) * 256 + c];
    hi[j] = f2bf(v);
    lo[j] = f2bf(v - bf2f(hi[j]));
  }
  *reinterpret_cast<ushort4v*>(Wt_hi + (size_t)c * 512 + kq * 4) = hi;
  *reinterpret_cast<ushort4v*>(Wt_lo + (size_t)c * 512 + kq * 4) = lo;
}

// ---------------- K1: h-tile via split MFMA; fused s1/s2/e2/e02 + ht bf16 ----------------
__global__ __launch_bounds__(256) void k_h(
    const float* __restrict__ doc, const unsigned short* __restrict__ Wt_hi,
    const unsigned short* __restrict__ Wt_lo, const float* __restrict__ Wb,
    const float* __restrict__ a,
    unsigned short* __restrict__ ht, float* __restrict__ s1,
    float* __restrict__ e2, float* __restrict__ e02)
{
  __shared__ __align__(16) short8 aH[2][2][64];   // [buf][rt][lane] 4 KB
  __shared__ __align__(16) short8 aL[2][2][64];   // 4 KB
  __shared__ float sred[4][2][32];                // 1 KB

  const int t = threadIdx.x, w = t >> 6, l = t & 63;
  const int lr = l & 15, lg = l >> 4;
  const int rb = blockIdx.x * 32;
  const int cb = w * 64;

  f32x4 acc[2][4];
#pragma unroll
  for (int rt = 0; rt < 2; ++rt)
#pragma unroll
    for (int ct = 0; ct < 4; ++ct) acc[rt][ct] = (f32x4){0.f, 0.f, 0.f, 0.f};

  const float* docp = doc + (size_t)(rb + w * 16 + lr) * 512 + lg * 8;  // valid for w<2

  f32x4 v0, v1;   // doc prefetch regs
  auto loadDoc = [&](int k0) { if (w < 2) {
      v0 = *reinterpret_cast<const f32x4*>(docp + k0);
      v1 = *reinterpret_cast<const f32x4*>(docp + k0 + 4);
  }};
  auto writeStage = [&](int pb) { if (w < 2) {
      union { short8 v; unsigned short u[8]; } hi, lo;
#pragma unroll
      for (int q = 0; q < 4; ++q) {
        hi.u[q] = f2bf(v0[q]);     lo.u[q] = f2bf(v0[q] - bf2f(hi.u[q]));
        hi.u[4+q] = f2bf(v1[q]);   lo.u[4+q] = f2bf(v1[q] - bf2f(hi.u[4+q]));
      }
      aH[pb][w][l] = hi.v;
      aL[pb][w][l] = lo.v;
  }};

  loadDoc(0); writeStage(0); loadDoc(32);

  for (int n = 0; n < 16; ++n) {
    const int kk = n * 32;
    const int par = n & 1;

    asm volatile("s_waitcnt lgkmcnt(0)\n\ts_barrier" ::: "memory");

    const short8 ah0 = aH[par][0][l];
    const short8 ah1 = aH[par][1][l];
    const short8 al0 = aL[par][0][l];
    const short8 al1 = aL[par][1][l];

    short8 bh[4], bl[4];
#pragma unroll
    for (int ct = 0; ct < 4; ++ct) {
      const size_t off = (size_t)(cb + ct * 16 + lr) * 512 + kk + lg * 8;
      bh[ct] = *reinterpret_cast<const short8*>(Wt_hi + off);
      bl[ct] = *reinterpret_cast<const short8*>(Wt_lo + off);
    }

    if (n + 1 < 16) writeStage(par ^ 1);
    if (n + 2 < 16) loadDoc((n + 2) * 32);

#pragma unroll
    for (int ct = 0; ct < 4; ++ct) {
      acc[0][ct] = __builtin_amdgcn_mfma_f32_16x16x32_bf16(ah0, bh[ct], acc[0][ct], 0, 0, 0);
      acc[1][ct] = __builtin_amdgcn_mfma_f32_16x16x32_bf16(ah1, bh[ct], acc[1][ct], 0, 0, 0);
      acc[0][ct] = __builtin_amdgcn_mfma_f32_16x16x32_bf16(ah0, bl[ct], acc[0][ct], 0, 0, 0);
      acc[1][ct] = __builtin_amdgcn_mfma_f32_16x16x32_bf16(ah1, bl[ct], acc[1][ct], 0, 0, 0);
      acc[0][ct] = __builtin_amdgcn_mfma_f32_16x16x32_bf16(al0, bh[ct], acc[0][ct], 0, 0, 0);
      acc[1][ct] = __builtin_amdgcn_mfma_f32_16x16x32_bf16(al1, bh[ct], acc[1][ct], 0, 0, 0);
    }
  }

  // bias add + ht write (C/D layout: col = cb+ct*16+lr, row = rb+rt*16+lg*4+q)
  float bias[4];
#pragma unroll
  for (int ct = 0; ct < 4; ++ct) bias[ct] = Wb[cb + ct * 16 + lr];
#pragma unroll
  for (int rt = 0; rt < 2; ++rt)
#pragma unroll
    for (int ct = 0; ct < 4; ++ct) {
#pragma unroll
      for (int q = 0; q < 4; ++q) acc[rt][ct][q] += bias[ct];
      ushort4v u;
#pragma unroll
      for (int q = 0; q < 4; ++q) u[q] = f2bf(acc[rt][ct][q]);
      *reinterpret_cast<ushort4v*>(
          ht + (size_t)(cb + ct * 16 + lr) * 8192 + rb + rt * 16 + lg * 4) = u;
    }

  // s1/s2: per-row dot with a1/a2 (this wave's 64 cols), reduce over lr, then waves
  float a1c[4], a2c[4];
#pragma unroll
  for (int ct = 0; ct < 4; ++ct) {
    a1c[ct] = a[cb + ct * 16 + lr];
    a2c[ct] = a[256 + cb + ct * 16 + lr];
  }
  float p1[2][4], p2[2][4];
#pragma unroll
  for (int rt = 0; rt < 2; ++rt)
#pragma unroll
    for (int q = 0; q < 4; ++q) {
      float x1 = 0.f, x2 = 0.f;
#pragma unroll
      for (int ct = 0; ct < 4; ++ct) {
        x1 = fmaf(acc[rt][ct][q], a1c[ct], x1);
        x2 = fmaf(acc[rt][ct][q], a2c[ct], x2);
      }
#pragma unroll
      for (int off = 1; off < 16; off <<= 1) {
        x1 += __shfl_xor(x1, off);
        x2 += __shfl_xor(x2, off);
      }
      p1[rt][q] = x1; p2[rt][q] = x2;
    }
  __syncthreads();
  if (lr == 0) {
#pragma unroll
    for (int rt = 0; rt < 2; ++rt)
#pragma unroll
      for (int q = 0; q < 4; ++q) {
        sred[w][0][rt * 16 + lg * 4 + q] = p1[rt][q];
        sred[w][1][rt * 16 + lg * 4 + q] = p2[rt][q];
      }
  }
  __syncthreads();
  if (t < 32) {
    float v1s = 0.f, v2s = 0.f;
#pragma unroll
    for (int ww = 0; ww < 4; ++ww) { v1s += sred[ww][0][t]; v2s += sred[ww][1][t]; }
    const int r = rb + t;
    s1[r] = v1s;
    e2[r] = __expf(v2s);
    e02[r] = __expf(SLOPE * v2s);
  }
}

// ---------------- K3: per-row Z -> rowinfo {E1*iz, E01*iz, T, iz} ----------------
__global__ __launch_bounds__(256) void k_z(
    const float* __restrict__ s1, const float* __restrict__ e2g,
    const float* __restrict__ e02g, const float* __restrict__ abp,
    float* __restrict__ rowinfo)
{
  __shared__ __align__(16) float es[8192];
  __shared__ __align__(16) float fs[8192];
  const int t = threadIdx.x;
  for (int i = t * 4; i < 8192; i += 1024) {
    *reinterpret_cast<f32x4*>(&es[i]) = *reinterpret_cast<const f32x4*>(e2g + i);
    *reinterpret_cast<f32x4*>(&fs[i]) = *reinterpret_cast<const f32x4*>(e02g + i);
  }
  __syncthreads();
  const int w = t >> 6, l = t & 63;
  const float ab = abp[0];
  const int rb = blockIdx.x * 16 + w * 4;
  float T[4], E1[4], E01[4];
#pragma unroll
  for (int rr = 0; rr < 4; ++rr) {
    const float s1a = s1[rb + rr] + ab;
    E1[rr] = __expf(s1a); E01[rr] = __expf(SLOPE * s1a); T[rr] = __expf(-s1a);
  }
  float zA[4] = {0.f,0.f,0.f,0.f}, zB[4] = {0.f,0.f,0.f,0.f};
  for (int i = l * 4; i < 8192; i += 256) {
    const f32x4 e = *reinterpret_cast<const f32x4*>(&es[i]);
    const f32x4 f = *reinterpret_cast<const f32x4*>(&fs[i]);
#pragma unroll
    for (int rr = 0; rr < 4; ++rr)
#pragma unroll
      for (int q = 0; q < 4; ++q) {
        const bool c = (e[q] >= T[rr]);
        zA[rr] += c ? e[q] : 0.f;
        zB[rr] += c ? 0.f : f[q];
      }
  }
#pragma unroll
  for (int rr = 0; rr < 4; ++rr) {
    float z = E1[rr] * zA[rr] + E01[rr] * zB[rr];
#pragma unroll
    for (int off = 32; off > 0; off >>= 1) z += __shfl_down(z, off);
    if (l == 0) {
      const float iz = 1.0f / z;
      f32x4 ri = (f32x4){E1[rr] * iz, E01[rr] * iz, T[rr], iz};
      *reinterpret_cast<f32x4*>(rowinfo + (size_t)(rb + rr) * 4) = ri;
    }
  }
}

// ---------------- K4: att + partial out via MFMA, split-K, deep-pipelined ----------------
// grid (KS, 128): x = k-slice (fastest -> XCD-aligned L2 ht slice), y = 64-row block.
// 4 waves, 32-k step. B-fragments double-buffered in REGISTERS, prefetched one
// window ahead and issued BEFORE that window's att stores -> consuming b(n) needs
// only vmcnt(>=8): att stores NEVER gate MFMA (loads+stores share vmcnt on CDNA),
// and b-load L2 latency is hidden by a full iteration. 2-unrolled loop for static
// register indexing (rule: runtime-indexed vector arrays spill to scratch).
__global__ __launch_bounds__(256, 2) void k_att(
    const float* __restrict__ rowinfo, const float* __restrict__ e2g,
    const float* __restrict__ e02g, const unsigned short* __restrict__ ht,
    float* __restrict__ att, float* __restrict__ part, int CHUNK)
{
  extern __shared__ __align__(16) char smem[];
  char* plsb  = smem;                                    // [2][4][64] short8 = 8 KB
  float* e2s  = reinterpret_cast<float*>(smem + 8192);   // CHUNK
  float* e02s = e2s + CHUNK;                             // CHUNK

  const int t = threadIdx.x, w = t >> 6, l = t & 63;
  const int lr = l & 15, lg = l >> 4;
  const int kbase = blockIdx.x * CHUNK;     // slice (fastest -> XCD)
  const int rb = blockIdx.y * 64;

  for (int i = t * 4; i < CHUNK; i += 1024) {
    *reinterpret_cast<f32x4*>(e2s + i)  = *reinterpret_cast<const f32x4*>(e2g + kbase + i);
    *reinterpret_cast<f32x4*>(e02s + i) = *reinterpret_cast<const f32x4*>(e02g + kbase + i);
  }

  // ---- writer role ----
  const int r8 = l >> 3, jc = l & 7;
  const int rowA = rb + w * 16 + r8;
  const int rowB = rowA + 8;
  const f32x4 riA = *reinterpret_cast<const f32x4*>(rowinfo + (size_t)rowA * 4);
  const f32x4 riB = *reinterpret_cast<const f32x4*>(rowinfo + (size_t)rowB * 4);
  const float E1zA = riA[0], E01zA = riA[1], TA = riA[2];
  const float E1zB = riB[0], E01zB = riB[1], TB = riB[2];
  float* attA = att + (size_t)rowA * 8192 + kbase + jc * 4;
  float* attB = att + (size_t)rowB * 8192 + kbase + jc * 4;
  const int fragA = w * 1024 + ((jc >> 1) * 16 + r8) * 16 + (jc & 1) * 8;
  const int fragB = fragA + 128;

  __syncthreads();

  auto gen = [&](int kw, int pb) {
    const f32x4 eA = *reinterpret_cast<const f32x4*>(e2s + kw + jc * 4);
    const f32x4 fA = *reinterpret_cast<const f32x4*>(e02s + kw + jc * 4);
    f32x4 pA, pB;
#pragma unroll
    for (int q = 0; q < 4; ++q) {
      const bool cA = (eA[q] >= TA);
      pA[q] = (cA ? E1zA : E01zA) * (cA ? eA[q] : fA[q]);
      const bool cB = (eA[q] >= TB);
      pB[q] = (cB ? E1zB : E01zB) * (cB ? eA[q] : fA[q]);
    }
    __builtin_nontemporal_store(pA, reinterpret_cast<f32x4*>(attA + kw));
    __builtin_nontemporal_store(pB, reinterpret_cast<f32x4*>(attB + kw));
    uint2 uA, uB;
    uA.x = cvt_pk_bf16(pA[0], pA[1]); uA.y = cvt_pk_bf16(pA[2], pA[3]);
    uB.x = cvt_pk_bf16(pB[0], pB[1]); uB.y = cvt_pk_bf16(pB[2], pB[3]);
    *reinterpret_cast<uint2*>(plsb + pb * 4096 + fragA) = uA;
    *reinterpret_cast<uint2*>(plsb + pb * 4096 + fragB) = uB;
  };

  const unsigned short* hbase = ht + (size_t)(w * 64 + lr) * 8192 + kbase + lg * 8;
  auto loadB = [&](short8* b, int n) {
    const int kk = n * 32;
#pragma unroll
    for (int ct = 0; ct < 4; ++ct)
      b[ct] = *reinterpret_cast<const short8*>(hbase + kk + (size_t)ct * 16 * 8192);
  };

  f32x4 acc[4][4];
#pragma unroll
  for (int rt = 0; rt < 4; ++rt)
#pragma unroll
    for (int ct = 0; ct < 4; ++ct) acc[rt][ct] = (f32x4){0.f, 0.f, 0.f, 0.f};

  auto mma = [&](const short8* b, const short8& af0, const short8& af1,
                 const short8& af2, const short8& af3) {
    __builtin_amdgcn_s_setprio(1);
    acc[0][0] = __builtin_amdgcn_mfma_f32_16x16x32_bf16(af0, b[0], acc[0][0], 0, 0, 0);
    acc[1][0] = __builtin_amdgcn_mfma_f32_16x16x32_bf16(af1, b[0], acc[1][0], 0, 0, 0);
    acc[2][0] = __builtin_amdgcn_mfma_f32_16x16x32_bf16(af2, b[0], acc[2][0], 0, 0, 0);
    acc[3][0] = __builtin_amdgcn_mfma_f32_16x16x32_bf16(af3, b[0], acc[3][0], 0, 0, 0);
    acc[0][1] = __builtin_amdgcn_mfma_f32_16x16x32_bf16(af0, b[1], acc[0][1], 0, 0, 0);
    acc[1][1] = __builtin_amdgcn_mfma_f32_16x16x32_bf16(af1, b[1], acc[1][1], 0, 0, 0);
    acc[2][1] = __builtin_amdgcn_mfma_f32_16x16x32_bf16(af2, b[1], acc[2][1], 0, 0, 0);
    acc[3][1] = __builtin_amdgcn_mfma_f32_16x16x32_bf16(af3, b[1], acc[3][1], 0, 0, 0);
    acc[0][2] = __builtin_amdgcn_mfma_f32_16x16x32_bf16(af0, b[2], acc[0][2], 0, 0, 0);
    acc[1][2] = __builtin_amdgcn_mfma_f32_16x16x32_bf16(af1, b[2], acc[1][2], 0, 0, 0);
    acc[2][2] = __builtin_amdgcn_mfma_f32_16x16x32_bf16(af2, b[2], acc[2][2], 0, 0, 0);
    acc[3][2] = __builtin_amdgcn_mfma_f32_16x16x32_bf16(af3, b[2], acc[3][2], 0, 0, 0);
    acc[0][3] = __builtin_amdgcn_mfma_f32_16x16x32_bf16(af0, b[3], acc[0][3], 0, 0, 0);
    acc[1][3] = __builtin_amdgcn_mfma_f32_16x16x32_bf16(af1, b[3], acc[1][3], 0, 0, 0);
    acc[2][3] = __builtin_amdgcn_mfma_f32_16x16x32_bf16(af2, b[3], acc[2][3], 0, 0, 0);
    acc[3][3] = __builtin_amdgcn_mfma_f32_16x16x32_bf16(af3, b[3], acc[3][3], 0, 0, 0);
    __builtin_amdgcn_s_setprio(0);
  };

  short8 bAr[4], bBr[4];
  loadB(bAr, 0);          // b(0) issued before gen(0)'s stores
  gen(0, 0);

  const int NIT = CHUNK / 32;   // even (KS in {1,2,4})
  const short8* buf0 = reinterpret_cast<const short8*>(plsb);
  const short8* buf1 = reinterpret_cast<const short8*>(plsb + 4096);

  for (int n = 0; n < NIT; n += 2) {
    // even window n: frags buf0, b regs bAr
    if (n + 1 < NIT) loadB(bBr, n + 1);
    asm volatile("s_waitcnt lgkmcnt(0)\n\ts_barrier" ::: "memory");
    {
      const short8 af0 = buf0[0 * 64 + l];
      const short8 af1 = buf0[1 * 64 + l];
      const short8 af2 = buf0[2 * 64 + l];
      const short8 af3 = buf0[3 * 64 + l];
      if (n + 1 < NIT) gen((n + 1) * 32, 1);
      mma(bAr, af0, af1, af2, af3);
    }
    if (n + 1 >= NIT) break;
    // odd window n+1: frags buf1, b regs bBr
    if (n + 2 < NIT) loadB(bAr, n + 2);
    asm volatile("s_waitcnt lgkmcnt(0)\n\ts_barrier" ::: "memory");
    {
      const short8 af0 = buf1[0 * 64 + l];
      const short8 af1 = buf1[1 * 64 + l];
      const short8 af2 = buf1[2 * 64 + l];
      const short8 af3 = buf1[3 * 64 + l];
      if (n + 2 < NIT) gen((n + 2) * 32, 0);
      mma(bBr, af0, af1, af2, af3);
    }
  }

  float* pb = part + (size_t)blockIdx.x * ((size_t)NROW * DDIM);
#pragma unroll
  for (int rt = 0; rt < 4; ++rt)
#pragma unroll
    for (int ct = 0; ct < 4; ++ct)
#pragma unroll
      for (int q = 0; q < 4; ++q)
        __builtin_nontemporal_store(acc[rt][ct][q],
            pb + (size_t)(rb + rt * 16 + lg * 4 + q) * 256 + w * 64 + ct * 16 + lr);
}

// ---------------- K5: out = lrelu(sum_k part[k]) ----------------
__global__ __launch_bounds__(256) void k_reduce(
    const float* __restrict__ part, float* __restrict__ out, int KS)
{
  const size_t idx = ((size_t)blockIdx.x * 256 + threadIdx.x) * 4;
  f32x4 s = __builtin_nontemporal_load(reinterpret_cast<const f32x4*>(part + idx));
  for (int k = 1; k < KS; ++k) {
    const f32x4 v = __builtin_nontemporal_load(
        reinterpret_cast<const f32x4*>(part + (size_t)k * NROW * DDIM + idx));
#pragma unroll
    for (int q = 0; q < 4; ++q) s[q] += v[q];
  }
#pragma unroll
  for (int q = 0; q < 4; ++q) s[q] = lrelu(s[q]);
  __builtin_nontemporal_store(s, reinterpret_cast<f32x4*>(out + idx));
}

extern "C" void kernel_launch(void* const* d_in, const int* in_sizes, int n_in,
                              void* d_out, int out_size, void* d_ws, size_t ws_size,
                              hipStream_t stream)
{
  const float* doc = (const float*)d_in[0];
  const float* W   = (const float*)d_in[1];
  const float* Wb  = (const float*)d_in[2];
  const float* a   = (const float*)d_in[3];
  const float* ab  = (const float*)d_in[4];

  float* out = (float*)d_out;                 // 8192*256
  float* att = out + (size_t)8192 * 256;      // 8192*8192

  char* ws = (char*)d_ws;
  unsigned short* ht    = (unsigned short*)ws;                              // 4 MB
  unsigned short* Wt_hi = (unsigned short*)(ws + (size_t)4 * 1024 * 1024);  // 256 KB
  unsigned short* Wt_lo = Wt_hi + (size_t)256 * 512;                        // 256 KB
  float* s1      = (float*)(ws + (size_t)4 * 1024 * 1024 + 512 * 1024);     // 32 KB
  float* e2      = s1 + 8192;
  float* e02     = e2 + 8192;
  float* rowinfo = e02 + 8192;                                              // 128 KB
  const size_t base = (size_t)5 * 1024 * 1024;
  const size_t partBytes = (size_t)NROW * DDIM * sizeof(float);             // 8 MB

  int KS = 1;
  for (int c = 4; c >= 1; c >>= 1)
    if (base + (size_t)c * partBytes <= ws_size) { KS = c; break; }
  float* part = (float*)(ws + base);
  const int CHUNK = NROW / KS;
  const size_t smem = 8192 + (size_t)2 * CHUNK * sizeof(float);

  hipLaunchKernelGGL(k_prep,   dim3(128),     dim3(256), 0,    stream, W, Wt_hi, Wt_lo);
  hipLaunchKernelGGL(k_h,      dim3(256),     dim3(256), 0,    stream, doc, Wt_hi, Wt_lo, Wb, a, ht, s1, e2, e02);
  hipLaunchKernelGGL(k_z,      dim3(512),     dim3(256), 0,    stream, s1, e2, e02, ab, rowinfo);
  hipLaunchKernelGGL(k_att,    dim3(KS, 128), dim3(256), smem, stream, rowinfo, e2, e02, ht, att, part, CHUNK);
  hipLaunchKernelGGL(k_reduce, dim3(2048),    dim3(256), 0,    stream, part, out, KS);
}

// Round 9
// 130.434 us; speedup vs baseline: 1.6538x; 1.0158x over previous
//
#include <hip/hip_runtime.h>
#include <hip/hip_bf16.h>

// GAT layer: h = doc@W + Wb; s1 = h@a1, s2 = h@a2;
// score[i,j] = lrelu(s1[i]+s2[j]+ab); att = softmax_rows(score); out = lrelu(att@h)
// N=8192, IN=512, D=256. Outputs: out (8192*256) then att (8192*8192), fp32.
//
// exp(lrelu(s1a+s2j)) = (s2j >= -s1a) ? exp(s1a)*e2[j] : exp(.1*s1a)*e02[j]
// -> no transcendentals in N^2 loops.
// h via bf16-split MFMA: x = hi+lo; hi*hi + hi*lo + lo*hi ~ fp32 (2^-17 rel).

typedef __attribute__((ext_vector_type(4))) float f32x4;
typedef __attribute__((ext_vector_type(8))) short short8;
typedef __attribute__((ext_vector_type(4))) unsigned short ushort4v;

#define SLOPE 0.1f
#define NROW 8192
#define DDIM 256

__device__ __forceinline__ float lrelu(float x){ return fmaxf(x, SLOPE * x); }

__device__ __forceinline__ unsigned short f2bf(float f){
  union { float f; unsigned u; } v; v.f = f;
  unsigned r = (v.u + 0x7fffu + ((v.u >> 16) & 1u)) >> 16;
  return (unsigned short)r;
}
__device__ __forceinline__ float bf2f(unsigned short u){
  union { unsigned u; float f; } v; v.u = (unsigned)u << 16; return v.f;
}
__device__ __forceinline__ unsigned cvt_pk_bf16(float lo, float hi){
  unsigned r;
  asm("v_cvt_pk_bf16_f32 %0, %1, %2" : "=v"(r) : "v"(lo), "v"(hi));
  return r;
}

// ---------------- K0: Wt_hi/Wt_lo [256][512] bf16 split-transpose of W ----------------
__global__ __launch_bounds__(256) void k_prep(
    const float* __restrict__ W,
    unsigned short* __restrict__ Wt_hi, unsigned short* __restrict__ Wt_lo)
{
  const int tid = blockIdx.x * 256 + threadIdx.x;   // 32768 total
  const int c = tid >> 7, kq = tid & 127;
  ushort4v hi, lo;
#pragma unroll
  for (int j = 0; j < 4; ++j) {
    const float v = W[(size_t)(kq * 4 + j) * 256 + c];
    hi[j] = f2bf(v);
    lo[j] = f2bf(v - bf2f(hi[j]));
  }
  *reinterpret_cast<ushort4v*>(Wt_hi + (size_t)c * 512 + kq * 4) = hi;
  *reinterpret_cast<ushort4v*>(Wt_lo + (size_t)c * 512 + kq * 4) = lo;
}

// ---------------- K1: h-tile via split MFMA; fused s1/s2/e2/e02 + ht bf16 ----------------
// 512 threads = 8 waves (2/SIMD). Block = 32 rows x 256 cols; wave w owns cols w*32..+31.
// Waves 0,1 stage doc hi/lo A-frags (identical protocol to 4-wave version).
__global__ __launch_bounds__(512, 2) void k_h(
    const float* __restrict__ doc, const unsigned short* __restrict__ Wt_hi,
    const unsigned short* __restrict__ Wt_lo, const float* __restrict__ Wb,
    const float* __restrict__ a,
    unsigned short* __restrict__ ht, float* __restrict__ s1,
    float* __restrict__ e2, float* __restrict__ e02)
{
  __shared__ __align__(16) short8 aH[2][2][64];   // [buf][rt][lane] 4 KB
  __shared__ __align__(16) short8 aL[2][2][64];   // 4 KB
  __shared__ float sred[8][2][32];                // 2 KB

  const int t = threadIdx.x, w = t >> 6, l = t & 63;
  const int lr = l & 15, lg = l >> 4;
  const int rb = blockIdx.x * 32;
  const int cb = w * 32;

  f32x4 acc[2][2];
#pragma unroll
  for (int rt = 0; rt < 2; ++rt)
#pragma unroll
    for (int ct = 0; ct < 2; ++ct) acc[rt][ct] = (f32x4){0.f, 0.f, 0.f, 0.f};

  const float* docp = doc + (size_t)(rb + w * 16 + lr) * 512 + lg * 8;  // valid for w<2

  f32x4 v0, v1;
  auto loadDoc = [&](int k0) { if (w < 2) {
      v0 = *reinterpret_cast<const f32x4*>(docp + k0);
      v1 = *reinterpret_cast<const f32x4*>(docp + k0 + 4);
  }};
  auto writeStage = [&](int pb) { if (w < 2) {
      union { short8 v; unsigned short u[8]; } hi, lo;
#pragma unroll
      for (int q = 0; q < 4; ++q) {
        hi.u[q] = f2bf(v0[q]);     lo.u[q] = f2bf(v0[q] - bf2f(hi.u[q]));
        hi.u[4+q] = f2bf(v1[q]);   lo.u[4+q] = f2bf(v1[q] - bf2f(hi.u[4+q]));
      }
      aH[pb][w][l] = hi.v;
      aL[pb][w][l] = lo.v;
  }};

  loadDoc(0); writeStage(0); loadDoc(32);

  for (int n = 0; n < 16; ++n) {
    const int kk = n * 32;
    const int par = n & 1;

    asm volatile("s_waitcnt lgkmcnt(0)\n\ts_barrier" ::: "memory");

    const short8 ah0 = aH[par][0][l];
    const short8 ah1 = aH[par][1][l];
    const short8 al0 = aL[par][0][l];
    const short8 al1 = aL[par][1][l];

    short8 bh[2], bl[2];
#pragma unroll
    for (int ct = 0; ct < 2; ++ct) {
      const size_t off = (size_t)(cb + ct * 16 + lr) * 512 + kk + lg * 8;
      bh[ct] = *reinterpret_cast<const short8*>(Wt_hi + off);
      bl[ct] = *reinterpret_cast<const short8*>(Wt_lo + off);
    }

    if (n + 1 < 16) writeStage(par ^ 1);
    if (n + 2 < 16) loadDoc((n + 2) * 32);

#pragma unroll
    for (int ct = 0; ct < 2; ++ct) {
      acc[0][ct] = __builtin_amdgcn_mfma_f32_16x16x32_bf16(ah0, bh[ct], acc[0][ct], 0, 0, 0);
      acc[1][ct] = __builtin_amdgcn_mfma_f32_16x16x32_bf16(ah1, bh[ct], acc[1][ct], 0, 0, 0);
      acc[0][ct] = __builtin_amdgcn_mfma_f32_16x16x32_bf16(ah0, bl[ct], acc[0][ct], 0, 0, 0);
      acc[1][ct] = __builtin_amdgcn_mfma_f32_16x16x32_bf16(ah1, bl[ct], acc[1][ct], 0, 0, 0);
      acc[0][ct] = __builtin_amdgcn_mfma_f32_16x16x32_bf16(al0, bh[ct], acc[0][ct], 0, 0, 0);
      acc[1][ct] = __builtin_amdgcn_mfma_f32_16x16x32_bf16(al1, bh[ct], acc[1][ct], 0, 0, 0);
    }
  }

  float bias[2];
#pragma unroll
  for (int ct = 0; ct < 2; ++ct) bias[ct] = Wb[cb + ct * 16 + lr];
#pragma unroll
  for (int rt = 0; rt < 2; ++rt)
#pragma unroll
    for (int ct = 0; ct < 2; ++ct) {
#pragma unroll
      for (int q = 0; q < 4; ++q) acc[rt][ct][q] += bias[ct];
      ushort4v u;
#pragma unroll
      for (int q = 0; q < 4; ++q) u[q] = f2bf(acc[rt][ct][q]);
      *reinterpret_cast<ushort4v*>(
          ht + (size_t)(cb + ct * 16 + lr) * 8192 + rb + rt * 16 + lg * 4) = u;
    }

  // s1/s2 over this wave's 32 cols; reduce over lr then waves
  float a1c[2], a2c[2];
#pragma unroll
  for (int ct = 0; ct < 2; ++ct) {
    a1c[ct] = a[cb + ct * 16 + lr];
    a2c[ct] = a[256 + cb + ct * 16 + lr];
  }
  float p1[2][4], p2[2][4];
#pragma unroll
  for (int rt = 0; rt < 2; ++rt)
#pragma unroll
    for (int q = 0; q < 4; ++q) {
      float x1 = 0.f, x2 = 0.f;
#pragma unroll
      for (int ct = 0; ct < 2; ++ct) {
        x1 = fmaf(acc[rt][ct][q], a1c[ct], x1);
        x2 = fmaf(acc[rt][ct][q], a2c[ct], x2);
      }
#pragma unroll
      for (int off = 1; off < 16; off <<= 1) {
        x1 += __shfl_xor(x1, off);
        x2 += __shfl_xor(x2, off);
      }
      p1[rt][q] = x1; p2[rt][q] = x2;
    }
  __syncthreads();
  if (lr == 0) {
#pragma unroll
    for (int rt = 0; rt < 2; ++rt)
#pragma unroll
      for (int q = 0; q < 4; ++q) {
        sred[w][0][rt * 16 + lg * 4 + q] = p1[rt][q];
        sred[w][1][rt * 16 + lg * 4 + q] = p2[rt][q];
      }
  }
  __syncthreads();
  if (t < 32) {
    float v1s = 0.f, v2s = 0.f;
#pragma unroll
    for (int ww = 0; ww < 8; ++ww) { v1s += sred[ww][0][t]; v2s += sred[ww][1][t]; }
    const int r = rb + t;
    s1[r] = v1s;
    e2[r] = __expf(v2s);
    e02[r] = __expf(SLOPE * v2s);
  }
}

// ---------------- K3: per-row Z -> rowinfo {E1*iz, E01*iz, T, iz} ----------------
__global__ __launch_bounds__(256) void k_z(
    const float* __restrict__ s1, const float* __restrict__ e2g,
    const float* __restrict__ e02g, const float* __restrict__ abp,
    float* __restrict__ rowinfo)
{
  __shared__ __align__(16) float es[8192];
  __shared__ __align__(16) float fs[8192];
  const int t = threadIdx.x;
  for (int i = t * 4; i < 8192; i += 1024) {
    *reinterpret_cast<f32x4*>(&es[i]) = *reinterpret_cast<const f32x4*>(e2g + i);
    *reinterpret_cast<f32x4*>(&fs[i]) = *reinterpret_cast<const f32x4*>(e02g + i);
  }
  __syncthreads();
  const int w = t >> 6, l = t & 63;
  const float ab = abp[0];
  const int rb = blockIdx.x * 16 + w * 4;
  float T[4], E1[4], E01[4];
#pragma unroll
  for (int rr = 0; rr < 4; ++rr) {
    const float s1a = s1[rb + rr] + ab;
    E1[rr] = __expf(s1a); E01[rr] = __expf(SLOPE * s1a); T[rr] = __expf(-s1a);
  }
  float zA[4] = {0.f,0.f,0.f,0.f}, zB[4] = {0.f,0.f,0.f,0.f};
  for (int i = l * 4; i < 8192; i += 256) {
    const f32x4 e = *reinterpret_cast<const f32x4*>(&es[i]);
    const f32x4 f = *reinterpret_cast<const f32x4*>(&fs[i]);
#pragma unroll
    for (int rr = 0; rr < 4; ++rr)
#pragma unroll
      for (int q = 0; q < 4; ++q) {
        const bool c = (e[q] >= T[rr]);
        zA[rr] += c ? e[q] : 0.f;
        zB[rr] += c ? 0.f : f[q];
      }
  }
#pragma unroll
  for (int rr = 0; rr < 4; ++rr) {
    float z = E1[rr] * zA[rr] + E01[rr] * zB[rr];
#pragma unroll
    for (int off = 32; off > 0; off >>= 1) z += __shfl_down(z, off);
    if (l == 0) {
      const float iz = 1.0f / z;
      f32x4 ri = (f32x4){E1[rr] * iz, E01[rr] * iz, T[rr], iz};
      *reinterpret_cast<f32x4*>(rowinfo + (size_t)(rb + rr) * 4) = ri;
    }
  }
}

// ---------------- K4: att + partial out via MFMA, split-K, deep-pipelined, 8 waves ----------------
// grid (KS, 128), block 512 = 8 waves (4/SIMD). 64 rows/block, 32-k step.
// Wave w: cols w*32..+31 (2 ct); generates p for rows rb+w*8..+7 (A-frag set w>>1,
// in-set lane-rows (w&1)*8+r). B double-buffered in regs, prefetched 1 window ahead,
// issued before that window's att stores -> stores never gate MFMA (shared vmcnt).
__global__ __launch_bounds__(512, 4) void k_att(
    const float* __restrict__ rowinfo, const float* __restrict__ e2g,
    const float* __restrict__ e02g, const unsigned short* __restrict__ ht,
    float* __restrict__ att, float* __restrict__ part, int CHUNK)
{
  extern __shared__ __align__(16) char smem[];
  char* plsb  = smem;                                    // [2][4][64] short8 = 8 KB
  float* e2s  = reinterpret_cast<float*>(smem + 8192);   // CHUNK
  float* e02s = e2s + CHUNK;                             // CHUNK

  const int t = threadIdx.x, w = t >> 6, l = t & 63;
  const int lr = l & 15, lg = l >> 4;
  const int kbase = blockIdx.x * CHUNK;     // slice (fastest -> XCD)
  const int rb = blockIdx.y * 64;

  for (int i = t * 4; i < CHUNK; i += 2048) {
    *reinterpret_cast<f32x4*>(e2s + i)  = *reinterpret_cast<const f32x4*>(e2g + kbase + i);
    *reinterpret_cast<f32x4*>(e02s + i) = *reinterpret_cast<const f32x4*>(e02g + kbase + i);
  }

  // ---- writer role: 8 rows per wave ----
  const int r = l >> 3, jc = l & 7;
  const int rowW = rb + w * 8 + r;
  const f32x4 ri = *reinterpret_cast<const f32x4*>(rowinfo + (size_t)rowW * 4);
  const float E1z = ri[0], E01z = ri[1], T = ri[2];
  float* attW = att + (size_t)rowW * 8192 + kbase + jc * 4;
  const int fragoff = (w >> 1) * 1024 + ((jc >> 1) * 16 + (w & 1) * 8 + r) * 16 + (jc & 1) * 8;

  __syncthreads();

  auto gen = [&](int kw, int pb) {
    const f32x4 eA = *reinterpret_cast<const f32x4*>(e2s + kw + jc * 4);
    const f32x4 fA = *reinterpret_cast<const f32x4*>(e02s + kw + jc * 4);
    f32x4 pA;
#pragma unroll
    for (int q = 0; q < 4; ++q) {
      const bool cA = (eA[q] >= T);
      pA[q] = (cA ? E1z : E01z) * (cA ? eA[q] : fA[q]);
    }
    __builtin_nontemporal_store(pA, reinterpret_cast<f32x4*>(attW + kw));
    uint2 u;
    u.x = cvt_pk_bf16(pA[0], pA[1]); u.y = cvt_pk_bf16(pA[2], pA[3]);
    *reinterpret_cast<uint2*>(plsb + pb * 4096 + fragoff) = u;
  };

  const unsigned short* hbase = ht + (size_t)(w * 32 + lr) * 8192 + kbase + lg * 8;
  auto loadB = [&](short8* b, int n) {
    const int kk = n * 32;
    b[0] = *reinterpret_cast<const short8*>(hbase + kk);
    b[1] = *reinterpret_cast<const short8*>(hbase + kk + (size_t)16 * 8192);
  };

  f32x4 acc[4][2];
#pragma unroll
  for (int rt = 0; rt < 4; ++rt)
#pragma unroll
    for (int ct = 0; ct < 2; ++ct) acc[rt][ct] = (f32x4){0.f, 0.f, 0.f, 0.f};

  auto mma = [&](const short8* b, const short8& af0, const short8& af1,
                 const short8& af2, const short8& af3) {
    __builtin_amdgcn_s_setprio(1);
    acc[0][0] = __builtin_amdgcn_mfma_f32_16x16x32_bf16(af0, b[0], acc[0][0], 0, 0, 0);
    acc[1][0] = __builtin_amdgcn_mfma_f32_16x16x32_bf16(af1, b[0], acc[1][0], 0, 0, 0);
    acc[2][0] = __builtin_amdgcn_mfma_f32_16x16x32_bf16(af2, b[0], acc[2][0], 0, 0, 0);
    acc[3][0] = __builtin_amdgcn_mfma_f32_16x16x32_bf16(af3, b[0], acc[3][0], 0, 0, 0);
    acc[0][1] = __builtin_amdgcn_mfma_f32_16x16x32_bf16(af0, b[1], acc[0][1], 0, 0, 0);
    acc[1][1] = __builtin_amdgcn_mfma_f32_16x16x32_bf16(af1, b[1], acc[1][1], 0, 0, 0);
    acc[2][1] = __builtin_amdgcn_mfma_f32_16x16x32_bf16(af2, b[1], acc[2][1], 0, 0, 0);
    acc[3][1] = __builtin_amdgcn_mfma_f32_16x16x32_bf16(af3, b[1], acc[3][1], 0, 0, 0);
    __builtin_amdgcn_s_setprio(0);
  };

  short8 bAr[2], bBr[2];
  loadB(bAr, 0);          // b(0) issued before gen(0)'s store
  gen(0, 0);

  const int NIT = CHUNK / 32;   // even
  const short8* buf0 = reinterpret_cast<const short8*>(plsb);
  const short8* buf1 = reinterpret_cast<const short8*>(plsb + 4096);

  for (int n = 0; n < NIT; n += 2) {
    if (n + 1 < NIT) loadB(bBr, n + 1);
    asm volatile("s_waitcnt lgkmcnt(0)\n\ts_barrier" ::: "memory");
    {
      const short8 af0 = buf0[0 * 64 + l];
      const short8 af1 = buf0[1 * 64 + l];
      const short8 af2 = buf0[2 * 64 + l];
      const short8 af3 = buf0[3 * 64 + l];
      if (n + 1 < NIT) gen((n + 1) * 32, 1);
      mma(bAr, af0, af1, af2, af3);
    }
    if (n + 1 >= NIT) break;
    if (n + 2 < NIT) loadB(bAr, n + 2);
    asm volatile("s_waitcnt lgkmcnt(0)\n\ts_barrier" ::: "memory");
    {
      const short8 af0 = buf1[0 * 64 + l];
      const short8 af1 = buf1[1 * 64 + l];
      const short8 af2 = buf1[2 * 64 + l];
      const short8 af3 = buf1[3 * 64 + l];
      if (n + 2 < NIT) gen((n + 2) * 32, 0);
      mma(bBr, af0, af1, af2, af3);
    }
  }

  float* pb = part + (size_t)blockIdx.x * ((size_t)NROW * DDIM);
#pragma unroll
  for (int rt = 0; rt < 4; ++rt)
#pragma unroll
    for (int ct = 0; ct < 2; ++ct)
#pragma unroll
      for (int q = 0; q < 4; ++q)
        __builtin_nontemporal_store(acc[rt][ct][q],
            pb + (size_t)(rb + rt * 16 + lg * 4 + q) * 256 + w * 32 + ct * 16 + lr);
}

// ---------------- K5: out = lrelu(sum_k part[k]) ----------------
__global__ __launch_bounds__(256) void k_reduce(
    const float* __restrict__ part, float* __restrict__ out, int KS)
{
  const size_t idx = ((size_t)blockIdx.x * 256 + threadIdx.x) * 4;
  f32x4 s = __builtin_nontemporal_load(reinterpret_cast<const f32x4*>(part + idx));
  for (int k = 1; k < KS; ++k) {
    const f32x4 v = __builtin_nontemporal_load(
        reinterpret_cast<const f32x4*>(part + (size_t)k * NROW * DDIM + idx));
#pragma unroll
    for (int q = 0; q < 4; ++q) s[q] += v[q];
  }
#pragma unroll
  for (int q = 0; q < 4; ++q) s[q] = lrelu(s[q]);
  __builtin_nontemporal_store(s, reinterpret_cast<f32x4*>(out + idx));
}

extern "C" void kernel_launch(void* const* d_in, const int* in_sizes, int n_in,
                              void* d_out, int out_size, void* d_ws, size_t ws_size,
                              hipStream_t stream)
{
  const float* doc = (const float*)d_in[0];
  const float* W   = (const float*)d_in[1];
  const float* Wb  = (const float*)d_in[2];
  const float* a   = (const float*)d_in[3];
  const float* ab  = (const float*)d_in[4];

  float* out = (float*)d_out;                 // 8192*256
  float* att = out + (size_t)8192 * 256;      // 8192*8192

  char* ws = (char*)d_ws;
  unsigned short* ht    = (unsigned short*)ws;                              // 4 MB
  unsigned short* Wt_hi = (unsigned short*)(ws + (size_t)4 * 1024 * 1024);  // 256 KB
  unsigned short* Wt_lo = Wt_hi + (size_t)256 * 512;                        // 256 KB
  float* s1      = (float*)(ws + (size_t)4 * 1024 * 1024 + 512 * 1024);     // 32 KB
  float* e2      = s1 + 8192;
  float* e02     = e2 + 8192;
  float* rowinfo = e02 + 8192;                                              // 128 KB
  const size_t base = (size_t)5 * 1024 * 1024;
  const size_t partBytes = (size_t)NROW * DDIM * sizeof(float);             // 8 MB

  int KS = 1;
  for (int c = 4; c >= 1; c >>= 1)
    if (base + (size_t)c * partBytes <= ws_size) { KS = c; break; }
  float* part = (float*)(ws + base);
  const int CHUNK = NROW / KS;
  const size_t smem = 8192 + (size_t)2 * CHUNK * sizeof(float);

  hipLaunchKernelGGL(k_prep,   dim3(128),     dim3(256), 0,    stream, W, Wt_hi, Wt_lo);
  hipLaunchKernelGGL(k_h,      dim3(256),     dim3(512), 0,    stream, doc, Wt_hi, Wt_lo, Wb, a, ht, s1, e2, e02);
  hipLaunchKernelGGL(k_z,      dim3(512),     dim3(256), 0,    stream, s1, e2, e02, ab, rowinfo);
  hipLaunchKernelGGL(k_att,    dim3(KS, 128), dim3(512), smem, stream, rowinfo, e2, e02, ht, att, part, CHUNK);
  hipLaunchKernelGGL(k_reduce, dim3(2048),    dim3(256), 0,    stream, part, out, KS);
}